// Round 1
// 2894.330 us; speedup vs baseline: 1.1417x; 1.1417x over previous
//
#include <hip/hip_runtime.h>
#include <hip/hip_bf16.h>
#include <stdint.h>

typedef unsigned short u16;
typedef unsigned int   u32;
typedef unsigned long long u64;
typedef float v2f __attribute__((ext_vector_type(2)));

#define B_    8
#define N_    8192
#define M_    2048
#define NS_   32
#define CIN_  64
#define ROWS_ (B_*M_*NS_)          // 524288
#define BIGF  1e10f
#define EPSF  1e-5f
#define INV_ROWS (1.0f/524288.0f)  // 2^-19, exact

__device__ __forceinline__ u16 f2bf(float f){
  u32 x=__float_as_uint(f);
  return (u16)((x + 0x7FFFu + ((x>>16)&1u))>>16);   // RNE
}
__device__ __forceinline__ float bf2f(u16 u){ return __uint_as_float(((u32)u)<<16); }

// ---------------------------------------------------------------- prep (fp32 weights in)
__global__ __launch_bounds__(256) void k_prep(
    const float* w0,const float* b0,const float* g0,const float* bt0,
    const float* w1,const float* b1,const float* g1,const float* bt1,
    const float* w2,const float* b2,const float* g2,const float* bt2,
    float* Wt0,float* Wt1,float* Wt2,
    float* biasf,float* gf,float* btf,float* stats)
{
  int tid=threadIdx.x;
  for (int i=tid;i<768;i+=256) stats[i]=0.f;
  for (int i=tid;i<67*64;i+=256){ int c=i>>6,o=i&63;  Wt0[c*64+o]=w0[o*67+c]; }
  for (int i=tid;i<64*64;i+=256){ int c=i>>6,o=i&63;  Wt1[c*64+o]=w1[o*64+c]; }
  for (int i=tid;i<64*128;i+=256){int c=i>>7,o=i&127; Wt2[c*128+o]=w2[o*64+c]; }
  if (tid<64){
    biasf[0*128+tid]=b0[tid]; gf[0*128+tid]=g0[tid]; btf[0*128+tid]=bt0[tid];
    biasf[1*128+tid]=b1[tid]; gf[1*128+tid]=g1[tid]; btf[1*128+tid]=bt1[tid];
  }
  if (tid<128){
    biasf[2*128+tid]=b2[tid]; gf[2*128+tid]=g2[tid]; btf[2*128+tid]=bt2[tid];
  }
}

// ------------------------------------------------------- feature transpose
__global__ __launch_bounds__(256) void k_tr(const float* __restrict__ feats, u16* __restrict__ featT)
{
  __shared__ float t[64][65];
  int bb=blockIdx.y, n0=blockIdx.x*64, tid=threadIdx.x;
  int a=tid&63, q=tid>>6;
  const float* fp = feats + (size_t)bb*CIN_*N_;
  #pragma unroll
  for (int s=0;s<16;s++){ int c=q*16+s; t[c][a]=fp[(size_t)c*N_ + n0 + a]; }
  __syncthreads();
  u16* op = featT + (size_t)bb*N_*CIN_;
  #pragma unroll
  for (int s=0;s<16;s++){ int n=q*16+s; op[(size_t)(n0+n)*CIN_ + a] = f2bf(t[a][n]); }
}

// ---------------------------------------------------------------- FPS
// R12-best config (512 thr, 16 pts/thread, PRE-update emission, exact f32 no-FMA,
// packed (dist<<32 | ~idx) key max) PLUS this round's changes:
//  (a) packed-f32 math: points processed as 8 float2 -> v_pk_add/v_pk_mul halve
//      the distance-loop VALU issue; fp contract OFF keeps it bit-exact vs ref.
//  (b) DPP wave max-reduce (row_shr 1/2/4/8 + row_bcast 15/31, result lane 63)
//      replaces 6 serial ds_bpermute shuffle levels (~400cy latency -> ~90cy VALU).
//  (c) depth-3 tree merge of the 8 wave keys.
// Keys are unique (idx embedded) and ops are IEEE-identical => same selections.
__device__ __forceinline__ u64 wave_max_key(u64 k){
  // full-wave max of non-negative u64 keys; bound_ctrl 0-fill is the max identity.
#define DPP_LVL(CTRL) { \
    u32 lo_=(u32)__builtin_amdgcn_update_dpp(0,(int)(u32)k,(CTRL),0xF,0xF,true); \
    u32 hi_=(u32)__builtin_amdgcn_update_dpp(0,(int)(u32)(k>>32),(CTRL),0xF,0xF,true); \
    u64 o_=((u64)hi_<<32)|(u64)lo_; \
    k=(o_>k)?o_:k; }
  DPP_LVL(0x111)  // row_shr:1
  DPP_LVL(0x112)  // row_shr:2
  DPP_LVL(0x114)  // row_shr:4
  DPP_LVL(0x118)  // row_shr:8
  DPP_LVL(0x142)  // row_bcast:15
  DPP_LVL(0x143)  // row_bcast:31  -> lane 63 holds wave max
#undef DPP_LVL
  return k;
}

__global__ __launch_bounds__(512) void k_fps(const float* __restrict__ xyz,
                                             float* __restrict__ nxyz, float* __restrict__ out0)
{
#pragma clang fp contract(off)
  __shared__ float sx[N_], sy[N_], sz[N_];
  __shared__ int sidx[M_];
  __shared__ u64 skey[2][8];
  int b=blockIdx.x, tid=threadIdx.x;
  const float* xp = xyz + (size_t)b*N_*3;
  for (int i=tid;i<N_;i+=512){ sx[i]=xp[i*3]; sy[i]=xp[i*3+1]; sz[i]=xp[i*3+2]; }
  __syncthreads();
  v2f px[8],py[8],pz[8],md[8];
  int base = tid*16;
  #pragma unroll
  for (int p=0;p<8;p++){
    px[p]=*(const v2f*)&sx[base+2*p];
    py[p]=*(const v2f*)&sy[base+2*p];
    pz[p]=*(const v2f*)&sz[base+2*p];
    v2f m0; m0[0]=BIGF; m0[1]=BIGF; md[p]=m0;
  }
  u32 invb = 0xFFFFFFFFu - (u32)base;
  int far=0;
  int lane=tid&63, wv=tid>>6;
  for (int step=0; step<M_; step++){
    if (tid==0) sidx[step]=far;          // PRE-update emission
    float cxs=sx[far], cys=sy[far], czs=sz[far];
    v2f cx; cx[0]=cxs; cx[1]=cxs;
    v2f cy; cy[0]=cys; cy[1]=cys;
    v2f cz; cz[0]=czs; cz[1]=czs;
    u64 kb=0;
    #pragma unroll
    for (int p=0;p<8;p++){
      v2f dx=px[p]-cx, dy=py[p]-cy, dz=pz[p]-cz;
      v2f d=(dx*dx+dy*dy)+dz*dz;         // contract off: same assoc as ((xx+yy)+zz)
      v2f m=__builtin_elementwise_min(md[p],d);
      md[p]=m;
      u64 k0=((u64)__float_as_uint(m[0])<<32)|(u64)(invb-(u32)(2*p));
      u64 k1=((u64)__float_as_uint(m[1])<<32)|(u64)(invb-(u32)(2*p+1));
      u64 kp=(k1>k0)?k1:k0;              // equal dist -> k0 (lower idx) wins: larger ~idx
      kb=(kp>kb)?kp:kb;
    }
    kb = wave_max_key(kb);
    int par = step & 1;
    if (lane==63) skey[par][wv]=kb;
    __syncthreads();                     // single barrier per step
    u64 a0=skey[par][0],a1=skey[par][1],a2=skey[par][2],a3=skey[par][3];
    u64 a4=skey[par][4],a5=skey[par][5],a6=skey[par][6],a7=skey[par][7];
    a0=(a1>a0)?a1:a0; a2=(a3>a2)?a3:a2; a4=(a5>a4)?a5:a4; a6=(a7>a6)?a7:a6;
    a0=(a2>a0)?a2:a0; a4=(a6>a4)?a6:a4;
    a0=(a4>a0)?a4:a0;
    far = (int)(0xFFFFFFFFu - (u32)(a0 & 0xFFFFFFFFull));
  }
  // f32 output: exact raw coordinates of selected points
  for (int i=tid;i<M_;i+=512){
    int id = sidx[i];
    float x=sx[id], y=sy[id], z=sz[id];
    size_t o=(size_t)(b*M_+i)*3;
    nxyz[o]=x; nxyz[o+1]=y; nxyz[o+2]=z;
    out0[o]=x; out0[o+1]=y; out0[o+2]=z;
  }
}

// ---------------------------------------------------------------- ball query
#define BQCAP 512
__global__ __launch_bounds__(512) void k_bq(const float* __restrict__ xyz, const float* __restrict__ nxyz,
                                            int* __restrict__ knn)
{
  __shared__ float4 sP[N_];
  __shared__ float candd[8][BQCAP];
  __shared__ u16  candi[8][BQCAP];
  int tid=threadIdx.x;
  int cid0 = blockIdx.x*8;
  int b = cid0 >> 11;
  const float* xp = xyz + (size_t)b*N_*3;
  for (int i=tid;i<N_;i+=512){
    float x=xp[i*3], y=xp[i*3+1], z=xp[i*3+2];
    float x2 = __fmul_rn(x,x);
    x2 = __fadd_rn(x2, __fmul_rn(y,y));
    x2 = __fadd_rn(x2, __fmul_rn(z,z));
    sP[i]=make_float4(x,y,z,x2);
  }
  __syncthreads();
  int w=tid>>6, lane=tid&63;
  int cid = cid0 + w;
  float cx=nxyz[(size_t)cid*3], cy=nxyz[(size_t)cid*3+1], cz=nxyz[(size_t)cid*3+2];
  float c2 = __fmul_rn(cx,cx);
  c2 = __fadd_rn(c2, __fmul_rn(cy,cy));
  c2 = __fadd_rn(c2, __fmul_rn(cz,cz));
  int cnt=0;
  for (int i0=0;i0<N_;i0+=64){
    int i=i0+lane;
    float4 p=sP[i];
    float dot = __fmul_rn(cx,p.x);
    dot = __fadd_rn(dot, __fmul_rn(cy,p.y));
    dot = __fadd_rn(dot, __fmul_rn(cz,p.z));
    float d2 = __fsub_rn(__fadd_rn(c2,p.w), __fmul_rn(2.0f,dot));
    float d = sqrtf(fmaxf(d2,0.f));
    bool in = (d <= 0.4f);
    u64 msk = __ballot(in);
    int pos = cnt + __popcll(msk & ((1ull<<lane)-1ull));
    if (in && pos<BQCAP){ candd[w][pos]=d; candi[w][pos]=(u16)i; }
    cnt += __popcll(msk);
  }
  int R = cnt<BQCAP ? cnt : BQCAP;
  int* kout = knn + (size_t)cid*NS_;
  if (R >= NS_){
    for (int s=0;s<NS_;s++){
      float bvv=3e38f; int bpp=1<<30;
      for (int j=lane;j<R;j+=64){
        float v=candd[w][j];
        if (v<bvv){ bvv=v; bpp=j; }
      }
      #pragma unroll
      for (int off=32;off>0;off>>=1){
        float ov=__shfl_down(bvv,off); int op=__shfl_down(bpp,off);
        if (ov<bvv || (ov==bvv && op<bpp)){ bvv=ov; bpp=op; }
      }
      if (lane==0){ kout[s]=candi[w][bpp]; candd[w][bpp]=3e38f; }
    }
  } else {
    if (lane<R) kout[lane]=candi[w][lane];
    int need = NS_-R, slot = R;
    for (int i0=0; i0<N_ && need>0; i0+=64){
      int i=i0+lane;
      float4 p=sP[i];
      float dot = __fmul_rn(cx,p.x);
      dot = __fadd_rn(dot, __fmul_rn(cy,p.y));
      dot = __fadd_rn(dot, __fmul_rn(cz,p.z));
      float d2 = __fsub_rn(__fadd_rn(c2,p.w), __fmul_rn(2.0f,dot));
      float d = sqrtf(fmaxf(d2,0.f));
      bool in = (d <= 0.4f);
      u64 mm = __ballot(!in);
      while (mm && need>0){
        int bpos = __ffsll((long long)mm)-1;
        if (lane==0) kout[slot] = i0+bpos;
        slot++; need--;
        mm &= mm-1;
      }
    }
  }
}

// ---------------------------------------------------------------- layer 0 (gather+concat fused)
__global__ __launch_bounds__(256) void k_mm0(const float* __restrict__ xyz, const u16* __restrict__ featT,
                                             const int* __restrict__ knn, const float* __restrict__ nxyz,
                                             const float* __restrict__ Wt0, const float* __restrict__ biasf,
                                             u16* __restrict__ Y0)
{
  __shared__ u16 Xs[256*70];
  __shared__ float Wl[67*64];
  int tid=threadIdx.x;
  for (int i=tid;i<67*64;i+=256) Wl[i]=Wt0[i];
  int base = blockIdx.x*256;
  {
    int row = base + tid;
    int bm  = row >> 5;
    int b   = row >> 16;
    int n   = knn[row];
    const float* cp = nxyz + (size_t)bm*3;
    const float* xp = xyz + ((size_t)b*N_ + n)*3;
    u16* xr = &Xs[tid*70];
    xr[0]=f2bf(xp[0]-cp[0]);
    xr[1]=f2bf(xp[1]-cp[1]);
    xr[2]=f2bf(xp[2]-cp[2]);
    const uint4* fp = (const uint4*)(featT + ((size_t)b*N_ + n)*CIN_);
    #pragma unroll
    for (int i=0;i<8;i++){
      uint4 v=fp[i];
      u16* d = xr + 3 + i*8;
      d[0]=(u16)(v.x&0xFFFFu); d[1]=(u16)(v.x>>16);
      d[2]=(u16)(v.y&0xFFFFu); d[3]=(u16)(v.y>>16);
      d[4]=(u16)(v.z&0xFFFFu); d[5]=(u16)(v.z>>16);
      d[6]=(u16)(v.w&0xFFFFu); d[7]=(u16)(v.w>>16);
    }
  }
  __syncthreads();
  int g=tid>>7, rt=tid&127;
  float acc0[32], acc1[32];
  #pragma unroll
  for (int j=0;j<32;j++){ acc0[j]=0.f; acc1[j]=0.f; }
  const u16* xa=&Xs[rt*70];
  const u16* xb=&Xs[(rt+128)*70];
  for (int c=0;c<67;c++){
    float a=bf2f(xa[c]);
    float bx=bf2f(xb[c]);
    const float4* wr=(const float4*)&Wl[c*64 + g*32];
    #pragma unroll
    for (int o=0;o<8;o++){
      float4 wv=wr[o];
      acc0[o*4+0]+=a*wv.x;  acc0[o*4+1]+=a*wv.y;  acc0[o*4+2]+=a*wv.z;  acc0[o*4+3]+=a*wv.w;
      acc1[o*4+0]+=bx*wv.x; acc1[o*4+1]+=bx*wv.y; acc1[o*4+2]+=bx*wv.z; acc1[o*4+3]+=bx*wv.w;
    }
  }
  float bb[32];
  #pragma unroll
  for (int j=0;j<32;j++) bb[j]=biasf[g*32+j];
  u16* y0p = Y0 + ((size_t)(base+rt))*64 + g*32;
  u16* y1p = Y0 + ((size_t)(base+rt+128))*64 + g*32;
  #pragma unroll
  for (int j=0;j<32;j++){
    y0p[j]=f2bf(acc0[j]+bb[j]);
    y1p[j]=f2bf(acc1[j]+bb[j]);
  }
}

// ---------------------------------------------------------------- channel stats (sum, sumsq)
template<int C>
__global__ __launch_bounds__(256) void k_stats(const u16* __restrict__ Y, float* __restrict__ statsOut)
{
  __shared__ float red[512];
  int tid=threadIdx.x;
  int c = tid & (C-1);
  int gp = tid / C;
  const int GPT = 256/C;
  int r0 = blockIdx.x*GPT + gp;
  int stride = gridDim.x*GPT;
  float s=0.f, ss=0.f;
  for (int r=r0; r<ROWS_; r+=stride){
    float v=bf2f(Y[(size_t)r*C + c]);
    s+=v; ss+=v*v;
  }
  red[tid*2]=s; red[tid*2+1]=ss;
  __syncthreads();
  if (tid<C){
    float a=0.f,b2=0.f;
    for (int q=0;q<GPT;q++){ a+=red[(q*C+tid)*2]; b2+=red[(q*C+tid)*2+1]; }
    atomicAdd(&statsOut[tid*2],a);
    atomicAdd(&statsOut[tid*2+1],b2);
  }
}

// ---------------------------------------------------------------- layer 1 (bn0+relu fused into stage; in-place)
__global__ __launch_bounds__(256) void k_mm1(u16* __restrict__ Y, const float* __restrict__ Wt1,
                                             const float* __restrict__ bias1, const float* __restrict__ gf0,
                                             const float* __restrict__ btf0, const float* __restrict__ stats0)
{
  __shared__ u16 Xs[256*66];
  __shared__ float Wl[64*64];
  __shared__ float sc[64], sh[64];
  int tid=threadIdx.x;
  if (tid<64){
    float mu = stats0[tid*2]*INV_ROWS;
    float var= stats0[tid*2+1]*INV_ROWS - mu*mu;
    float rs = 1.0f/sqrtf(var+EPSF);
    float s  = rs*gf0[tid];
    sc[tid]=s; sh[tid]=btf0[tid]-mu*s;
  }
  for (int i=tid;i<64*64;i+=256) Wl[i]=Wt1[i];
  __syncthreads();
  size_t base=(size_t)blockIdx.x*256;
  for (int i=tid;i<2048;i+=256){
    int rl=i>>3, c0=(i&7)*8;
    uint4 v=*(const uint4*)(Y + (base+rl)*64 + c0);
    u32 arr[4]={v.x,v.y,v.z,v.w};
    u16* d=&Xs[rl*66+c0];
    #pragma unroll
    for (int q=0;q<4;q++){
      int cc=c0+q*2;
      float lo=bf2f((u16)(arr[q]&0xFFFFu));
      float hi=bf2f((u16)(arr[q]>>16));
      lo=fmaxf(0.f, lo*sc[cc]+sh[cc]);
      hi=fmaxf(0.f, hi*sc[cc+1]+sh[cc+1]);
      d[q*2]=f2bf(lo); d[q*2+1]=f2bf(hi);
    }
  }
  __syncthreads();
  int g=tid>>7, rt=tid&127;
  float acc0[32], acc1[32];
  #pragma unroll
  for (int j=0;j<32;j++){ acc0[j]=0.f; acc1[j]=0.f; }
  const u16* xa=&Xs[rt*66];
  const u16* xb=&Xs[(rt+128)*66];
  for (int c=0;c<64;c++){
    float a=bf2f(xa[c]);
    float bx=bf2f(xb[c]);
    const float4* wr=(const float4*)&Wl[c*64 + g*32];
    #pragma unroll
    for (int o=0;o<8;o++){
      float4 wv=wr[o];
      acc0[o*4+0]+=a*wv.x;  acc0[o*4+1]+=a*wv.y;  acc0[o*4+2]+=a*wv.z;  acc0[o*4+3]+=a*wv.w;
      acc1[o*4+0]+=bx*wv.x; acc1[o*4+1]+=bx*wv.y; acc1[o*4+2]+=bx*wv.z; acc1[o*4+3]+=bx*wv.w;
    }
  }
  float bb[32];
  #pragma unroll
  for (int j=0;j<32;j++) bb[j]=bias1[g*32+j];
  u16* y0p = Y + (base+rt)*64 + g*32;
  u16* y1p = Y + (base+rt+128)*64 + g*32;
  #pragma unroll
  for (int j=0;j<32;j++){
    y0p[j]=f2bf(acc0[j]+bb[j]);
    y1p[j]=f2bf(acc1[j]+bb[j]);
  }
}

// ---------------------------------------------------------------- layer 2: stats + RAW maxpool (Y2 never stored)
__global__ __launch_bounds__(256) void k_mm2a(const u16* __restrict__ Y1, const float* __restrict__ Wt2,
                                              const float* __restrict__ bias2, const float* __restrict__ gf1,
                                              const float* __restrict__ btf1, const float* __restrict__ stats1,
                                              float* __restrict__ stats2, float* __restrict__ out1)
{
  __shared__ u16 Xs[128*66];
  __shared__ float Wl[64*128];
  __shared__ float sc[64], sh[64];
  __shared__ float res[4][128];
  int tid=threadIdx.x;
  if (tid<64){
    float mu = stats1[tid*2]*INV_ROWS;
    float var= stats1[tid*2+1]*INV_ROWS - mu*mu;
    float rs = 1.0f/sqrtf(var+EPSF);
    float s  = rs*gf1[tid];
    sc[tid]=s; sh[tid]=btf1[tid]-mu*s;
  }
  for (int i=tid;i<64*128;i+=256) Wl[i]=Wt2[i];
  int g=tid>>6, rt=tid&63;
  float bb[32];
  #pragma unroll
  for (int j=0;j<32;j++) bb[j]=bias2[g*32+j];
  float sSum[32], sSq[32];
  #pragma unroll
  for (int j=0;j<32;j++){ sSum[j]=0.f; sSq[j]=0.f; }
  __syncthreads();
  for (int tile=blockIdx.x; tile<4096; tile+=gridDim.x){
    size_t base=(size_t)tile*128;
    for (int i=tid;i<1024;i+=256){
      int rl=i>>3, c0=(i&7)*8;
      uint4 v=*(const uint4*)(Y1 + (base+rl)*64 + c0);
      u32 arr[4]={v.x,v.y,v.z,v.w};
      u16* d=&Xs[rl*66+c0];
      #pragma unroll
      for (int q=0;q<4;q++){
        int cc=c0+q*2;
        float lo=bf2f((u16)(arr[q]&0xFFFFu));
        float hi=bf2f((u16)(arr[q]>>16));
        lo=fmaxf(0.f, lo*sc[cc]+sh[cc]);
        hi=fmaxf(0.f, hi*sc[cc+1]+sh[cc+1]);
        d[q*2]=f2bf(lo); d[q*2+1]=f2bf(hi);
      }
    }
    __syncthreads();
    float acc0[32], acc1[32];
    #pragma unroll
    for (int j=0;j<32;j++){ acc0[j]=0.f; acc1[j]=0.f; }
    const u16* xa=&Xs[rt*66];
    const u16* xb=&Xs[(rt+64)*66];
    for (int c=0;c<64;c++){
      float a=bf2f(xa[c]);
      float bx=bf2f(xb[c]);
      const float4* wr=(const float4*)&Wl[c*128 + g*32];
      #pragma unroll
      for (int o=0;o<8;o++){
        float4 wv=wr[o];
        acc0[o*4+0]+=a*wv.x;  acc0[o*4+1]+=a*wv.y;  acc0[o*4+2]+=a*wv.z;  acc0[o*4+3]+=a*wv.w;
        acc1[o*4+0]+=bx*wv.x; acc1[o*4+1]+=bx*wv.y; acc1[o*4+2]+=bx*wv.z; acc1[o*4+3]+=bx*wv.w;
      }
    }
    #pragma unroll
    for (int j=0;j<32;j++){
      float y0=acc0[j]+bb[j], y1=acc1[j]+bb[j];
      sSum[j]+=y0+y1;
      sSq[j] +=y0*y0+y1*y1;
      float a=y0, b2=y1;
      #pragma unroll
      for (int off=16;off>0;off>>=1){
        a = fmaxf(a, __shfl_down(a, off, 32));
        b2= fmaxf(b2,__shfl_down(b2,off, 32));
      }
      if ((rt&31)==0){
        int o=g*32+j;
        res[rt>>5][o]     = a;
        res[2+(rt>>5)][o] = b2;
      }
    }
    __syncthreads();
    int bm0 = tile*4;
    for (int e=tid;e<512;e+=256){
      int gr=e>>7, o=e&127;
      int bm=bm0+gr; int bi=bm>>11, m=bm&2047;
      out1[((size_t)bi*128+o)*M_ + m] = res[gr][o];
    }
    __syncthreads();
  }
  #pragma unroll
  for (int off=32;off>0;off>>=1){
    #pragma unroll
    for (int j=0;j<32;j++){
      sSum[j]+=__shfl_down(sSum[j],off);
      sSq[j] +=__shfl_down(sSq[j],off);
    }
  }
  if (rt==0){
    #pragma unroll
    for (int j=0;j<32;j++){
      atomicAdd(&stats2[(g*32+j)*2],  sSum[j]);
      atomicAdd(&stats2[(g*32+j)*2+1],sSq[j]);
    }
  }
}

// ---------------------------------------------------------------- final pool: in-place BN2+ReLU on raw maxes
__global__ __launch_bounds__(256) void k_pool(float* __restrict__ out1, const float* __restrict__ stats2,
                                              const float* __restrict__ gf2, const float* __restrict__ btf2)
{
  int idx = blockIdx.x*256 + threadIdx.x;     // 8*128*2048 = 2097152 elements
  int o = (idx >> 11) & 127;
  float mu = stats2[o*2]*INV_ROWS;
  float var= stats2[o*2+1]*INV_ROWS - mu*mu;
  float rs = 1.0f/sqrtf(var+EPSF);
  float s  = rs*gf2[o];
  float sh = btf2[o]-mu*s;
  out1[idx] = fmaxf(0.f, out1[idx]*s + sh);
}

// ---------------------------------------------------------------- launch
extern "C" void kernel_launch(void* const* d_in, const int* in_sizes, int n_in,
                              void* d_out, int out_size, void* d_ws, size_t ws_size,
                              hipStream_t stream)
{
  (void)in_sizes; (void)n_in; (void)out_size; (void)ws_size;
  const float* xyz =(const float*)d_in[0];
  const float* feat=(const float*)d_in[1];
  const float* w0=(const float*)d_in[2],  *b0=(const float*)d_in[3],  *g0=(const float*)d_in[4],  *bt0=(const float*)d_in[5];
  const float* w1=(const float*)d_in[6],  *b1=(const float*)d_in[7],  *g1=(const float*)d_in[8],  *bt1=(const float*)d_in[9];
  const float* w2=(const float*)d_in[10], *b2=(const float*)d_in[11], *g2=(const float*)d_in[12], *bt2=(const float*)d_in[13];
  float* out0=(float*)d_out;
  float* out1=out0 + (size_t)B_*M_*3;

  char* ws=(char*)d_ws;
  float* nxyz =(float*)(ws);              // 196608 B
  int*   knn  =(int*)  (ws + 262144);     // 2097152
  float* Wt0  =(float*)(ws + 2359296);    // 17408
  float* Wt1  =(float*)(ws + 2376704);    // 16384
  float* Wt2  =(float*)(ws + 2393088);    // 32768
  float* biasf=(float*)(ws + 2425856);    // 1536
  float* gfp  =(float*)(ws + 2427392);    // 1536
  float* btfp =(float*)(ws + 2428928);    // 1536
  float* stats=(float*)(ws + 2430464);    // 3072
  u16*   featT=(u16*)  (ws + 2433536);    // 8388608
  u16*   Y0   =(u16*)  (ws + 10822144);   // 67108864  (total ~78 MB)

  k_prep<<<1,256,0,stream>>>(w0,b0,g0,bt0,w1,b1,g1,bt1,w2,b2,g2,bt2,Wt0,Wt1,Wt2,biasf,gfp,btfp,stats);
  k_tr<<<dim3(128,8),256,0,stream>>>(feat, featT);
  k_fps<<<B_,512,0,stream>>>(xyz, nxyz, out0);
  k_bq<<<2048,512,0,stream>>>(xyz, nxyz, knn);
  k_mm0<<<2048,256,0,stream>>>(xyz, featT, knn, nxyz, Wt0, biasf+0, Y0);
  k_stats<64><<<512,256,0,stream>>>(Y0, stats+0);
  k_mm1<<<2048,256,0,stream>>>(Y0, Wt1, biasf+128, gfp+0, btfp+0, stats+0);
  k_stats<64><<<512,256,0,stream>>>(Y0, stats+256);
  k_mm2a<<<512,256,0,stream>>>(Y0, Wt2, biasf+256, gfp+128, btfp+128, stats+256, stats+512, out1);
  k_pool<<<8192,256,0,stream>>>(out1, stats+512, gfp+256, btfp+256);
}

// Round 2
// 2837.742 us; speedup vs baseline: 1.1645x; 1.0199x over previous
//
#include <hip/hip_runtime.h>
#include <hip/hip_bf16.h>
#include <stdint.h>

typedef unsigned short u16;
typedef unsigned int   u32;
typedef unsigned long long u64;
typedef float v2f __attribute__((ext_vector_type(2)));

#define B_    8
#define N_    8192
#define M_    2048
#define NS_   32
#define CIN_  64
#define ROWS_ (B_*M_*NS_)          // 524288
#define BIGF  1e10f
#define EPSF  1e-5f
#define INV_ROWS (1.0f/524288.0f)  // 2^-19, exact

__device__ __forceinline__ u16 f2bf(float f){
  u32 x=__float_as_uint(f);
  return (u16)((x + 0x7FFFu + ((x>>16)&1u))>>16);   // RNE
}
__device__ __forceinline__ float bf2f(u16 u){ return __uint_as_float(((u32)u)<<16); }

// DPP full-wave max of non-negative u64 keys; result lands in lane 63.
// bound_ctrl 0-fill is the identity for max of non-negative keys.
__device__ __forceinline__ u64 wave_max_key(u64 k){
#define DPP_LVL(CTRL) { \
    u32 lo_=(u32)__builtin_amdgcn_update_dpp(0,(int)(u32)k,(CTRL),0xF,0xF,true); \
    u32 hi_=(u32)__builtin_amdgcn_update_dpp(0,(int)(u32)(k>>32),(CTRL),0xF,0xF,true); \
    u64 o_=((u64)hi_<<32)|(u64)lo_; \
    k=(o_>k)?o_:k; }
  DPP_LVL(0x111)  // row_shr:1
  DPP_LVL(0x112)  // row_shr:2
  DPP_LVL(0x114)  // row_shr:4
  DPP_LVL(0x118)  // row_shr:8
  DPP_LVL(0x142)  // row_bcast:15
  DPP_LVL(0x143)  // row_bcast:31  -> lane 63 holds wave max
#undef DPP_LVL
  return k;
}

// ---------------------------------------------------------------- prep (fp32 weights in)
__global__ __launch_bounds__(256) void k_prep(
    const float* w0,const float* b0,const float* g0,const float* bt0,
    const float* w1,const float* b1,const float* g1,const float* bt1,
    const float* w2,const float* b2,const float* g2,const float* bt2,
    float* Wt0,float* Wt1,float* Wt2,
    float* biasf,float* gf,float* btf,float* stats)
{
  int tid=threadIdx.x;
  for (int i=tid;i<768;i+=256) stats[i]=0.f;
  for (int i=tid;i<67*64;i+=256){ int c=i>>6,o=i&63;  Wt0[c*64+o]=w0[o*67+c]; }
  for (int i=tid;i<64*64;i+=256){ int c=i>>6,o=i&63;  Wt1[c*64+o]=w1[o*64+c]; }
  for (int i=tid;i<64*128;i+=256){int c=i>>7,o=i&127; Wt2[c*128+o]=w2[o*64+c]; }
  if (tid<64){
    biasf[0*128+tid]=b0[tid]; gf[0*128+tid]=g0[tid]; btf[0*128+tid]=bt0[tid];
    biasf[1*128+tid]=b1[tid]; gf[1*128+tid]=g1[tid]; btf[1*128+tid]=bt1[tid];
  }
  if (tid<128){
    biasf[2*128+tid]=b2[tid]; gf[2*128+tid]=g2[tid]; btf[2*128+tid]=bt2[tid];
  }
}

// ------------------------------------------------------- feature transpose
__global__ __launch_bounds__(256) void k_tr(const float* __restrict__ feats, u16* __restrict__ featT)
{
  __shared__ float t[64][65];
  int bb=blockIdx.y, n0=blockIdx.x*64, tid=threadIdx.x;
  int a=tid&63, q=tid>>6;
  const float* fp = feats + (size_t)bb*CIN_*N_;
  #pragma unroll
  for (int s=0;s<16;s++){ int c=q*16+s; t[c][a]=fp[(size_t)c*N_ + n0 + a]; }
  __syncthreads();
  u16* op = featT + (size_t)bb*N_*CIN_;
  #pragma unroll
  for (int s=0;s<16;s++){ int n=q*16+s; op[(size_t)(n0+n)*CIN_ + a] = f2bf(t[a][n]); }
}

// ---------------------------------------------------------------- FPS
// R12-best 512-thr/16-pt config + R1 packed-f32 + DPP ladder. This round:
// the 8-key LDS publish + per-thread 8-load merge tree is replaced by ONE
// ds_max_u64 (LDS atomicMax) into a 3-slot rotating cell. Slot s%3 is
// published in epoch s, read (broadcast ds_read_b64) in epoch s+1, reset in
// epoch s+2 -> every reuse is separated by a barrier, race-free with one
// barrier/step. Keys unique (idx embedded), IEEE ops unchanged => identical
// selections.
__global__ __launch_bounds__(512) void k_fps(const float* __restrict__ xyz,
                                             float* __restrict__ nxyz, float* __restrict__ out0)
{
#pragma clang fp contract(off)
  __shared__ float sx[N_], sy[N_], sz[N_];
  __shared__ int sidx[M_];
  __shared__ u64 smax[3];
  int b=blockIdx.x, tid=threadIdx.x;
  const float* xp = xyz + (size_t)b*N_*3;
  if (tid<3) smax[tid]=0ull;
  for (int i=tid;i<N_;i+=512){ sx[i]=xp[i*3]; sy[i]=xp[i*3+1]; sz[i]=xp[i*3+2]; }
  __syncthreads();
  v2f px[8],py[8],pz[8],md[8];
  int base = tid*16;
  #pragma unroll
  for (int p=0;p<8;p++){
    px[p]=*(const v2f*)&sx[base+2*p];
    py[p]=*(const v2f*)&sy[base+2*p];
    pz[p]=*(const v2f*)&sz[base+2*p];
    v2f m0; m0[0]=BIGF; m0[1]=BIGF; md[p]=m0;
  }
  u32 invb = 0xFFFFFFFFu - (u32)base;
  int far=0;
  int lane=tid&63;
  for (int step=0; step<M_; step++){
    if (tid==0) sidx[step]=far;          // PRE-update emission
    float cxs=sx[far], cys=sy[far], czs=sz[far];
    v2f cx; cx[0]=cxs; cx[1]=cxs;
    v2f cy; cy[0]=cys; cy[1]=cys;
    v2f cz; cz[0]=czs; cz[1]=czs;
    u64 kb=0;
    #pragma unroll
    for (int p=0;p<8;p++){
      v2f dx=px[p]-cx, dy=py[p]-cy, dz=pz[p]-cz;
      v2f d=(dx*dx+dy*dy)+dz*dz;         // contract off: same assoc as ((xx+yy)+zz)
      v2f m=__builtin_elementwise_min(md[p],d);
      md[p]=m;
      u64 k0=((u64)__float_as_uint(m[0])<<32)|(u64)(invb-(u32)(2*p));
      u64 k1=((u64)__float_as_uint(m[1])<<32)|(u64)(invb-(u32)(2*p+1));
      u64 kp=(k1>k0)?k1:k0;              // equal dist -> k0 (lower idx) wins: larger ~idx
      kb=(kp>kb)?kp:kb;
    }
    kb = wave_max_key(kb);
    if (lane==63) atomicMax(&smax[step%3], kb);   // ds_max_u64, 8 waves -> 1 cell
    if (tid==0) smax[(step+1)%3]=0ull;            // reset slot for step+1 (its last
                                                  // read was epoch step-1: barrier-separated)
    __syncthreads();                     // single barrier per step
    u64 wk = smax[step%3];               // broadcast read
    far = (int)(0xFFFFFFFFu - (u32)(wk & 0xFFFFFFFFull));
  }
  // f32 output: exact raw coordinates of selected points
  for (int i=tid;i<M_;i+=512){
    int id = sidx[i];
    float x=sx[id], y=sy[id], z=sz[id];
    size_t o=(size_t)(b*M_+i)*3;
    nxyz[o]=x; nxyz[o+1]=y; nxyz[o+2]=z;
    out0[o]=x; out0[o+1]=y; out0[o+2]=z;
  }
}

// ---------------------------------------------------------------- ball query
// Selection loop: 12 serial ds_bpermute shuffles per pass -> u64-key DPP min
// ladder (min == ~max(~k), reusing wave_max_key). Key = bits(d)<<32 | pos:
// min value then min position == original (ov<bvv)||(ov==bvv&&op<bpp) tiebreak.
#define BQCAP 512
__global__ __launch_bounds__(512) void k_bq(const float* __restrict__ xyz, const float* __restrict__ nxyz,
                                            int* __restrict__ knn)
{
  __shared__ float4 sP[N_];
  __shared__ float candd[8][BQCAP];
  __shared__ u16  candi[8][BQCAP];
  int tid=threadIdx.x;
  int cid0 = blockIdx.x*8;
  int b = cid0 >> 11;
  const float* xp = xyz + (size_t)b*N_*3;
  for (int i=tid;i<N_;i+=512){
    float x=xp[i*3], y=xp[i*3+1], z=xp[i*3+2];
    float x2 = __fmul_rn(x,x);
    x2 = __fadd_rn(x2, __fmul_rn(y,y));
    x2 = __fadd_rn(x2, __fmul_rn(z,z));
    sP[i]=make_float4(x,y,z,x2);
  }
  __syncthreads();
  int w=tid>>6, lane=tid&63;
  int cid = cid0 + w;
  float cx=nxyz[(size_t)cid*3], cy=nxyz[(size_t)cid*3+1], cz=nxyz[(size_t)cid*3+2];
  float c2 = __fmul_rn(cx,cx);
  c2 = __fadd_rn(c2, __fmul_rn(cy,cy));
  c2 = __fadd_rn(c2, __fmul_rn(cz,cz));
  int cnt=0;
  for (int i0=0;i0<N_;i0+=64){
    int i=i0+lane;
    float4 p=sP[i];
    float dot = __fmul_rn(cx,p.x);
    dot = __fadd_rn(dot, __fmul_rn(cy,p.y));
    dot = __fadd_rn(dot, __fmul_rn(cz,p.z));
    float d2 = __fsub_rn(__fadd_rn(c2,p.w), __fmul_rn(2.0f,dot));
    float d = sqrtf(fmaxf(d2,0.f));
    bool in = (d <= 0.4f);
    u64 msk = __ballot(in);
    int pos = cnt + __popcll(msk & ((1ull<<lane)-1ull));
    if (in && pos<BQCAP){ candd[w][pos]=d; candi[w][pos]=(u16)i; }
    cnt += __popcll(msk);
  }
  int R = cnt<BQCAP ? cnt : BQCAP;
  int* kout = knn + (size_t)cid*NS_;
  if (R >= NS_){
    for (int s=0;s<NS_;s++){
      u64 kb = ~0ull;                    // min identity
      for (int j=lane;j<R;j+=64){
        float v=candd[w][j];
        u64 k = ((u64)__float_as_uint(v)<<32) | (u64)(u32)j;
        kb = (k<kb)?k:kb;
      }
      u64 inv = wave_max_key(~kb);       // min via complemented max
      if (lane==63){
        u64 kw = ~inv;
        int bpp = (int)(u32)(kw & 0xFFFFFFFFull);
        kout[s]=candi[w][bpp];
        candd[w][bpp]=3e38f;             // same-wave DS in-order: visible to next pass
      }
    }
  } else {
    if (lane<R) kout[lane]=candi[w][lane];
    int need = NS_-R, slot = R;
    for (int i0=0; i0<N_ && need>0; i0+=64){
      int i=i0+lane;
      float4 p=sP[i];
      float dot = __fmul_rn(cx,p.x);
      dot = __fadd_rn(dot, __fmul_rn(cy,p.y));
      dot = __fadd_rn(dot, __fmul_rn(cz,p.z));
      float d2 = __fsub_rn(__fadd_rn(c2,p.w), __fmul_rn(2.0f,dot));
      float d = sqrtf(fmaxf(d2,0.f));
      bool in = (d <= 0.4f);
      u64 mm = __ballot(!in);
      while (mm && need>0){
        int bpos = __ffsll((long long)mm)-1;
        if (lane==0) kout[slot] = i0+bpos;
        slot++; need--;
        mm &= mm-1;
      }
    }
  }
}

// ---------------------------------------------------------------- layer 0 (gather+concat fused)
__global__ __launch_bounds__(256) void k_mm0(const float* __restrict__ xyz, const u16* __restrict__ featT,
                                             const int* __restrict__ knn, const float* __restrict__ nxyz,
                                             const float* __restrict__ Wt0, const float* __restrict__ biasf,
                                             u16* __restrict__ Y0)
{
  __shared__ u16 Xs[256*70];
  __shared__ float Wl[67*64];
  int tid=threadIdx.x;
  for (int i=tid;i<67*64;i+=256) Wl[i]=Wt0[i];
  int base = blockIdx.x*256;
  {
    int row = base + tid;
    int bm  = row >> 5;
    int b   = row >> 16;
    int n   = knn[row];
    const float* cp = nxyz + (size_t)bm*3;
    const float* xp = xyz + ((size_t)b*N_ + n)*3;
    u16* xr = &Xs[tid*70];
    xr[0]=f2bf(xp[0]-cp[0]);
    xr[1]=f2bf(xp[1]-cp[1]);
    xr[2]=f2bf(xp[2]-cp[2]);
    const uint4* fp = (const uint4*)(featT + ((size_t)b*N_ + n)*CIN_);
    #pragma unroll
    for (int i=0;i<8;i++){
      uint4 v=fp[i];
      u16* d = xr + 3 + i*8;
      d[0]=(u16)(v.x&0xFFFFu); d[1]=(u16)(v.x>>16);
      d[2]=(u16)(v.y&0xFFFFu); d[3]=(u16)(v.y>>16);
      d[4]=(u16)(v.z&0xFFFFu); d[5]=(u16)(v.z>>16);
      d[6]=(u16)(v.w&0xFFFFu); d[7]=(u16)(v.w>>16);
    }
  }
  __syncthreads();
  int g=tid>>7, rt=tid&127;
  float acc0[32], acc1[32];
  #pragma unroll
  for (int j=0;j<32;j++){ acc0[j]=0.f; acc1[j]=0.f; }
  const u16* xa=&Xs[rt*70];
  const u16* xb=&Xs[(rt+128)*70];
  for (int c=0;c<67;c++){
    float a=bf2f(xa[c]);
    float bx=bf2f(xb[c]);
    const float4* wr=(const float4*)&Wl[c*64 + g*32];
    #pragma unroll
    for (int o=0;o<8;o++){
      float4 wv=wr[o];
      acc0[o*4+0]+=a*wv.x;  acc0[o*4+1]+=a*wv.y;  acc0[o*4+2]+=a*wv.z;  acc0[o*4+3]+=a*wv.w;
      acc1[o*4+0]+=bx*wv.x; acc1[o*4+1]+=bx*wv.y; acc1[o*4+2]+=bx*wv.z; acc1[o*4+3]+=bx*wv.w;
    }
  }
  float bb[32];
  #pragma unroll
  for (int j=0;j<32;j++) bb[j]=biasf[g*32+j];
  u16* y0p = Y0 + ((size_t)(base+rt))*64 + g*32;
  u16* y1p = Y0 + ((size_t)(base+rt+128))*64 + g*32;
  #pragma unroll
  for (int j=0;j<32;j++){
    y0p[j]=f2bf(acc0[j]+bb[j]);
    y1p[j]=f2bf(acc1[j]+bb[j]);
  }
}

// ---------------------------------------------------------------- channel stats (sum, sumsq)
// Vectorized uint4 loads (16B/lane), wave-shfl partial reduce, 128 blocks ->
// 16k global atomics (128/address) instead of 65k (512/address).
template<int C>
__global__ __launch_bounds__(256) void k_stats(const u16* __restrict__ Y, float* __restrict__ statsOut)
{
  __shared__ float sred[4][128];
  int tid=threadIdx.x;
  int c0=(tid&7)*8;          // 8 channels per thread
  int rg=tid>>3;             // 32 row-groups per block
  float s[8], ss[8];
  #pragma unroll
  for (int k=0;k<8;k++){ s[k]=0.f; ss[k]=0.f; }
  for (size_t r=(size_t)blockIdx.x*32+rg; r<ROWS_; r+=(size_t)gridDim.x*32){
    uint4 v=*(const uint4*)&Y[r*64+c0];
    u32 a[4]={v.x,v.y,v.z,v.w};
    #pragma unroll
    for (int q=0;q<4;q++){
      float lo=bf2f((u16)(a[q]&0xFFFFu));
      float hi=bf2f((u16)(a[q]>>16));
      s[q*2]+=lo;   ss[q*2]+=lo*lo;
      s[q*2+1]+=hi; ss[q*2+1]+=hi*hi;
    }
  }
  #pragma unroll
  for (int off=32; off>=8; off>>=1){
    #pragma unroll
    for (int k=0;k<8;k++){
      s[k]+=__shfl_down(s[k],off);
      ss[k]+=__shfl_down(ss[k],off);
    }
  }
  int lane=tid&63, wv=tid>>6;
  if (lane<8){
    #pragma unroll
    for (int k=0;k<8;k++){
      int ch=lane*8+k;
      sred[wv][ch]=s[k];
      sred[wv][64+ch]=ss[k];
    }
  }
  __syncthreads();
  if (tid<128){
    float a=sred[0][tid]+sred[1][tid]+sred[2][tid]+sred[3][tid];
    int ch=tid&63, which=tid>>6;
    atomicAdd(&statsOut[ch*2+which], a);
  }
}

// ---------------------------------------------------------------- layer 1 (bn0+relu fused into stage; in-place)
__global__ __launch_bounds__(256) void k_mm1(u16* __restrict__ Y, const float* __restrict__ Wt1,
                                             const float* __restrict__ bias1, const float* __restrict__ gf0,
                                             const float* __restrict__ btf0, const float* __restrict__ stats0)
{
  __shared__ u16 Xs[256*66];
  __shared__ float Wl[64*64];
  __shared__ float sc[64], sh[64];
  int tid=threadIdx.x;
  if (tid<64){
    float mu = stats0[tid*2]*INV_ROWS;
    float var= stats0[tid*2+1]*INV_ROWS - mu*mu;
    float rs = 1.0f/sqrtf(var+EPSF);
    float s  = rs*gf0[tid];
    sc[tid]=s; sh[tid]=btf0[tid]-mu*s;
  }
  for (int i=tid;i<64*64;i+=256) Wl[i]=Wt1[i];
  __syncthreads();
  size_t base=(size_t)blockIdx.x*256;
  for (int i=tid;i<2048;i+=256){
    int rl=i>>3, c0=(i&7)*8;
    uint4 v=*(const uint4*)(Y + (base+rl)*64 + c0);
    u32 arr[4]={v.x,v.y,v.z,v.w};
    u16* d=&Xs[rl*66+c0];
    #pragma unroll
    for (int q=0;q<4;q++){
      int cc=c0+q*2;
      float lo=bf2f((u16)(arr[q]&0xFFFFu));
      float hi=bf2f((u16)(arr[q]>>16));
      lo=fmaxf(0.f, lo*sc[cc]+sh[cc]);
      hi=fmaxf(0.f, hi*sc[cc+1]+sh[cc+1]);
      d[q*2]=f2bf(lo); d[q*2+1]=f2bf(hi);
    }
  }
  __syncthreads();
  int g=tid>>7, rt=tid&127;
  float acc0[32], acc1[32];
  #pragma unroll
  for (int j=0;j<32;j++){ acc0[j]=0.f; acc1[j]=0.f; }
  const u16* xa=&Xs[rt*66];
  const u16* xb=&Xs[(rt+128)*66];
  for (int c=0;c<64;c++){
    float a=bf2f(xa[c]);
    float bx=bf2f(xb[c]);
    const float4* wr=(const float4*)&Wl[c*64 + g*32];
    #pragma unroll
    for (int o=0;o<8;o++){
      float4 wv=wr[o];
      acc0[o*4+0]+=a*wv.x;  acc0[o*4+1]+=a*wv.y;  acc0[o*4+2]+=a*wv.z;  acc0[o*4+3]+=a*wv.w;
      acc1[o*4+0]+=bx*wv.x; acc1[o*4+1]+=bx*wv.y; acc1[o*4+2]+=bx*wv.z; acc1[o*4+3]+=bx*wv.w;
    }
  }
  float bb[32];
  #pragma unroll
  for (int j=0;j<32;j++) bb[j]=bias1[g*32+j];
  u16* y0p = Y + (base+rt)*64 + g*32;
  u16* y1p = Y + (base+rt+128)*64 + g*32;
  #pragma unroll
  for (int j=0;j<32;j++){
    y0p[j]=f2bf(acc0[j]+bb[j]);
    y1p[j]=f2bf(acc1[j]+bb[j]);
  }
}

// ---------------------------------------------------------------- layer 2: stats + RAW maxpool (Y2 never stored)
__global__ __launch_bounds__(256) void k_mm2a(const u16* __restrict__ Y1, const float* __restrict__ Wt2,
                                              const float* __restrict__ bias2, const float* __restrict__ gf1,
                                              const float* __restrict__ btf1, const float* __restrict__ stats1,
                                              float* __restrict__ stats2, float* __restrict__ out1)
{
  __shared__ u16 Xs[128*66];
  __shared__ float Wl[64*128];
  __shared__ float sc[64], sh[64];
  __shared__ float res[4][128];
  int tid=threadIdx.x;
  if (tid<64){
    float mu = stats1[tid*2]*INV_ROWS;
    float var= stats1[tid*2+1]*INV_ROWS - mu*mu;
    float rs = 1.0f/sqrtf(var+EPSF);
    float s  = rs*gf1[tid];
    sc[tid]=s; sh[tid]=btf1[tid]-mu*s;
  }
  for (int i=tid;i<64*128;i+=256) Wl[i]=Wt2[i];
  int g=tid>>6, rt=tid&63;
  float bb[32];
  #pragma unroll
  for (int j=0;j<32;j++) bb[j]=bias2[g*32+j];
  float sSum[32], sSq[32];
  #pragma unroll
  for (int j=0;j<32;j++){ sSum[j]=0.f; sSq[j]=0.f; }
  __syncthreads();
  for (int tile=blockIdx.x; tile<4096; tile+=gridDim.x){
    size_t base=(size_t)tile*128;
    for (int i=tid;i<1024;i+=256){
      int rl=i>>3, c0=(i&7)*8;
      uint4 v=*(const uint4*)(Y1 + (base+rl)*64 + c0);
      u32 arr[4]={v.x,v.y,v.z,v.w};
      u16* d=&Xs[rl*66+c0];
      #pragma unroll
      for (int q=0;q<4;q++){
        int cc=c0+q*2;
        float lo=bf2f((u16)(arr[q]&0xFFFFu));
        float hi=bf2f((u16)(arr[q]>>16));
        lo=fmaxf(0.f, lo*sc[cc]+sh[cc]);
        hi=fmaxf(0.f, hi*sc[cc+1]+sh[cc+1]);
        d[q*2]=f2bf(lo); d[q*2+1]=f2bf(hi);
      }
    }
    __syncthreads();
    float acc0[32], acc1[32];
    #pragma unroll
    for (int j=0;j<32;j++){ acc0[j]=0.f; acc1[j]=0.f; }
    const u16* xa=&Xs[rt*66];
    const u16* xb=&Xs[(rt+64)*66];
    for (int c=0;c<64;c++){
      float a=bf2f(xa[c]);
      float bx=bf2f(xb[c]);
      const float4* wr=(const float4*)&Wl[c*128 + g*32];
      #pragma unroll
      for (int o=0;o<8;o++){
        float4 wv=wr[o];
        acc0[o*4+0]+=a*wv.x;  acc0[o*4+1]+=a*wv.y;  acc0[o*4+2]+=a*wv.z;  acc0[o*4+3]+=a*wv.w;
        acc1[o*4+0]+=bx*wv.x; acc1[o*4+1]+=bx*wv.y; acc1[o*4+2]+=bx*wv.z; acc1[o*4+3]+=bx*wv.w;
      }
    }
    #pragma unroll
    for (int j=0;j<32;j++){
      float y0=acc0[j]+bb[j], y1=acc1[j]+bb[j];
      sSum[j]+=y0+y1;
      sSq[j] +=y0*y0+y1*y1;
      float a=y0, b2=y1;
      #pragma unroll
      for (int off=16;off>0;off>>=1){
        a = fmaxf(a, __shfl_down(a, off, 32));
        b2= fmaxf(b2,__shfl_down(b2,off, 32));
      }
      if ((rt&31)==0){
        int o=g*32+j;
        res[rt>>5][o]     = a;
        res[2+(rt>>5)][o] = b2;
      }
    }
    __syncthreads();
    int bm0 = tile*4;
    for (int e=tid;e<512;e+=256){
      int gr=e>>7, o=e&127;
      int bm=bm0+gr; int bi=bm>>11, m=bm&2047;
      out1[((size_t)bi*128+o)*M_ + m] = res[gr][o];
    }
    __syncthreads();
  }
  #pragma unroll
  for (int off=32;off>0;off>>=1){
    #pragma unroll
    for (int j=0;j<32;j++){
      sSum[j]+=__shfl_down(sSum[j],off);
      sSq[j] +=__shfl_down(sSq[j],off);
    }
  }
  if (rt==0){
    #pragma unroll
    for (int j=0;j<32;j++){
      atomicAdd(&stats2[(g*32+j)*2],  sSum[j]);
      atomicAdd(&stats2[(g*32+j)*2+1],sSq[j]);
    }
  }
}

// ---------------------------------------------------------------- final pool: in-place BN2+ReLU on raw maxes
__global__ __launch_bounds__(256) void k_pool(float* __restrict__ out1, const float* __restrict__ stats2,
                                              const float* __restrict__ gf2, const float* __restrict__ btf2)
{
  int idx = blockIdx.x*256 + threadIdx.x;     // 8*128*2048 = 2097152 elements
  int o = (idx >> 11) & 127;
  float mu = stats2[o*2]*INV_ROWS;
  float var= stats2[o*2+1]*INV_ROWS - mu*mu;
  float rs = 1.0f/sqrtf(var+EPSF);
  float s  = rs*gf2[o];
  float sh = btf2[o]-mu*s;
  out1[idx] = fmaxf(0.f, out1[idx]*s + sh);
}

// ---------------------------------------------------------------- launch
extern "C" void kernel_launch(void* const* d_in, const int* in_sizes, int n_in,
                              void* d_out, int out_size, void* d_ws, size_t ws_size,
                              hipStream_t stream)
{
  (void)in_sizes; (void)n_in; (void)out_size; (void)ws_size;
  const float* xyz =(const float*)d_in[0];
  const float* feat=(const float*)d_in[1];
  const float* w0=(const float*)d_in[2],  *b0=(const float*)d_in[3],  *g0=(const float*)d_in[4],  *bt0=(const float*)d_in[5];
  const float* w1=(const float*)d_in[6],  *b1=(const float*)d_in[7],  *g1=(const float*)d_in[8],  *bt1=(const float*)d_in[9];
  const float* w2=(const float*)d_in[10], *b2=(const float*)d_in[11], *g2=(const float*)d_in[12], *bt2=(const float*)d_in[13];
  float* out0=(float*)d_out;
  float* out1=out0 + (size_t)B_*M_*3;

  char* ws=(char*)d_ws;
  float* nxyz =(float*)(ws);              // 196608 B
  int*   knn  =(int*)  (ws + 262144);     // 2097152
  float* Wt0  =(float*)(ws + 2359296);    // 17408
  float* Wt1  =(float*)(ws + 2376704);    // 16384
  float* Wt2  =(float*)(ws + 2393088);    // 32768
  float* biasf=(float*)(ws + 2425856);    // 1536
  float* gfp  =(float*)(ws + 2427392);    // 1536
  float* btfp =(float*)(ws + 2428928);    // 1536
  float* stats=(float*)(ws + 2430464);    // 3072
  u16*   featT=(u16*)  (ws + 2433536);    // 8388608
  u16*   Y0   =(u16*)  (ws + 10822144);   // 67108864  (total ~78 MB)

  k_prep<<<1,256,0,stream>>>(w0,b0,g0,bt0,w1,b1,g1,bt1,w2,b2,g2,bt2,Wt0,Wt1,Wt2,biasf,gfp,btfp,stats);
  k_tr<<<dim3(128,8),256,0,stream>>>(feat, featT);
  k_fps<<<B_,512,0,stream>>>(xyz, nxyz, out0);
  k_bq<<<2048,512,0,stream>>>(xyz, nxyz, knn);
  k_mm0<<<2048,256,0,stream>>>(xyz, featT, knn, nxyz, Wt0, biasf+0, Y0);
  k_stats<64><<<128,256,0,stream>>>(Y0, stats+0);
  k_mm1<<<2048,256,0,stream>>>(Y0, Wt1, biasf+128, gfp+0, btfp+0, stats+0);
  k_stats<64><<<128,256,0,stream>>>(Y0, stats+256);
  k_mm2a<<<512,256,0,stream>>>(Y0, Wt2, biasf+256, gfp+128, btfp+128, stats+256, stats+512, out1);
  k_pool<<<8192,256,0,stream>>>(out1, stats+512, gfp+256, btfp+256);
}

// Round 4
// 2771.831 us; speedup vs baseline: 1.1922x; 1.0238x over previous
//
#include <hip/hip_runtime.h>
#include <hip/hip_bf16.h>
#include <stdint.h>

typedef unsigned short u16;
typedef unsigned int   u32;
typedef unsigned long long u64;
typedef float v2f __attribute__((ext_vector_type(2)));

#define B_    8
#define N_    8192
#define M_    2048
#define NS_   32
#define CIN_  64
#define ROWS_ (B_*M_*NS_)          // 524288
#define BIGF  1e10f
#define EPSF  1e-5f
#define INV_ROWS (1.0f/524288.0f)  // 2^-19, exact

__device__ __forceinline__ u16 f2bf(float f){
  u32 x=__float_as_uint(f);
  return (u16)((x + 0x7FFFu + ((x>>16)&1u))>>16);   // RNE
}
__device__ __forceinline__ float bf2f(u16 u){ return __uint_as_float(((u32)u)<<16); }

// ---- packed f32 helpers (VOP3P; both sources must be aligned VGPR pairs) ----
__device__ __forceinline__ v2f pk_add(v2f a, v2f b){
  v2f r; asm("v_pk_add_f32 %0, %1, %2" : "=v"(r) : "v"(a), "v"(b)); return r; }
__device__ __forceinline__ v2f pk_mul(v2f a, v2f b){
  v2f r; asm("v_pk_mul_f32 %0, %1, %2" : "=v"(r) : "v"(a), "v"(b)); return r; }

// DPP full-wave max of u32 (result valid in lane 63). 0-fill identity: values >= 0.
__device__ __forceinline__ u32 wave_max_u32(u32 k){
#define LVL(C) { u32 o_=(u32)__builtin_amdgcn_update_dpp(0,(int)k,(C),0xF,0xF,true); k=(o_>k)?o_:k; }
  LVL(0x111)  // row_shr:1
  LVL(0x112)  // row_shr:2
  LVL(0x114)  // row_shr:4
  LVL(0x118)  // row_shr:8
  LVL(0x142)  // row_bcast:15
  LVL(0x143)  // row_bcast:31
#undef LVL
  return k;
}

// DPP full-wave max of non-negative u64 keys; result lands in lane 63 (bq uses this).
__device__ __forceinline__ u64 wave_max_key(u64 k){
#define DPP_LVL(CTRL) { \
    u32 lo_=(u32)__builtin_amdgcn_update_dpp(0,(int)(u32)k,(CTRL),0xF,0xF,true); \
    u32 hi_=(u32)__builtin_amdgcn_update_dpp(0,(int)(u32)(k>>32),(CTRL),0xF,0xF,true); \
    u64 o_=((u64)hi_<<32)|(u64)lo_; \
    k=(o_>k)?o_:k; }
  DPP_LVL(0x111)
  DPP_LVL(0x112)
  DPP_LVL(0x114)
  DPP_LVL(0x118)
  DPP_LVL(0x142)
  DPP_LVL(0x143)
#undef DPP_LVL
  return k;
}

// ---------------------------------------------------------------- prep (fp32 weights in)
__global__ __launch_bounds__(256) void k_prep(
    const float* w0,const float* b0,const float* g0,const float* bt0,
    const float* w1,const float* b1,const float* g1,const float* bt1,
    const float* w2,const float* b2,const float* g2,const float* bt2,
    float* Wt0,float* Wt1,float* Wt2,
    float* biasf,float* gf,float* btf,float* stats)
{
  int tid=threadIdx.x;
  for (int i=tid;i<768;i+=256) stats[i]=0.f;
  for (int i=tid;i<67*64;i+=256){ int c=i>>6,o=i&63;  Wt0[c*64+o]=w0[o*67+c]; }
  for (int i=tid;i<64*64;i+=256){ int c=i>>6,o=i&63;  Wt1[c*64+o]=w1[o*64+c]; }
  for (int i=tid;i<64*128;i+=256){int c=i>>7,o=i&127; Wt2[c*128+o]=w2[o*64+c]; }
  if (tid<64){
    biasf[0*128+tid]=b0[tid]; gf[0*128+tid]=g0[tid]; btf[0*128+tid]=bt0[tid];
    biasf[1*128+tid]=b1[tid]; gf[1*128+tid]=g1[tid]; btf[1*128+tid]=bt1[tid];
  }
  if (tid<128){
    biasf[2*128+tid]=b2[tid]; gf[2*128+tid]=g2[tid]; btf[2*128+tid]=bt2[tid];
  }
}

// ------------------------------------------------------- feature transpose
__global__ __launch_bounds__(256) void k_tr(const float* __restrict__ feats, u16* __restrict__ featT)
{
  __shared__ float t[64][65];
  int bb=blockIdx.y, n0=blockIdx.x*64, tid=threadIdx.x;
  int a=tid&63, q=tid>>6;
  const float* fp = feats + (size_t)bb*CIN_*N_;
  #pragma unroll
  for (int s=0;s<16;s++){ int c=q*16+s; t[c][a]=fp[(size_t)c*N_ + n0 + a]; }
  __syncthreads();
  u16* op = featT + (size_t)bb*N_*CIN_;
  #pragma unroll
  for (int s=0;s<16;s++){ int n=q*16+s; op[(size_t)(n0+n)*CIN_ + a] = f2bf(t[a][n]); }
}

// ---------------------------------------------------------------- FPS
// 512 thr / 16 pts-per-thread / PRE-update emission / one barrier per step.
// (a) forced v_pk_add/mul (VOP3P, pair operands; centroid splatted to a pair
//     once per step -- the R3 op_sel_hi scalar form doesn't assemble);
// (b) no per-point u64 keys: running v2f max + once-per-step 16-elem index scan;
// (c) wave reduce = two u32 DPP ladders (value max, then min global index among
//     matching lanes; f32>=0 so uint order == float order);
// (d) cross-wave merge = R1 parity skey[2][8] + 8-load tree (R2 ds_max regressed).
// Selection bit-identical: same IEEE ops/assoc, same (dist, lowest-idx) tie-break.
__global__ __launch_bounds__(512) void k_fps(const float* __restrict__ xyz,
                                             float* __restrict__ nxyz, float* __restrict__ out0)
{
#pragma clang fp contract(off)
  __shared__ float sx[N_], sy[N_], sz[N_];
  __shared__ int sidx[M_];
  __shared__ u64 skey[2][8];
  int b=blockIdx.x, tid=threadIdx.x;
  const float* xp = xyz + (size_t)b*N_*3;
  for (int i=tid;i<N_;i+=512){ sx[i]=xp[i*3]; sy[i]=xp[i*3+1]; sz[i]=xp[i*3+2]; }
  __syncthreads();
  v2f px[8],py[8],pz[8],md[8];
  int base = tid*16;
  #pragma unroll
  for (int p=0;p<8;p++){
    px[p]=*(const v2f*)&sx[base+2*p];
    py[p]=*(const v2f*)&sy[base+2*p];
    pz[p]=*(const v2f*)&sz[base+2*p];
    v2f m0; m0[0]=BIGF; m0[1]=BIGF; md[p]=m0;
  }
  u32 invb = 0xFFFFFFFFu - (u32)base;
  int far=0;
  int lane=tid&63, wv=tid>>6;
  for (int step=0; step<M_; step++){
    if (tid==0) sidx[step]=far;          // PRE-update emission (off critical path)
    float cxs=sx[far], cys=sy[far], czs=sz[far];
    v2f ncx; ncx[0]=-cxs; ncx[1]=-cxs;   // splat -centroid to reg pairs (a-c == a+(-c))
    v2f ncy; ncy[0]=-cys; ncy[1]=-cys;
    v2f ncz; ncz[0]=-czs; ncz[1]=-czs;
    v2f rm; rm[0]=0.f; rm[1]=0.f;        // distances >= 0
    #pragma unroll
    for (int p=0;p<8;p++){
      v2f dx=pk_add(px[p],ncx);
      v2f dy=pk_add(py[p],ncy);
      v2f dz=pk_add(pz[p],ncz);
      v2f d = pk_add(pk_add(pk_mul(dx,dx), pk_mul(dy,dy)), pk_mul(dz,dz));
      v2f m = __builtin_elementwise_min(md[p], d);
      md[p]=m;
      rm = __builtin_elementwise_max(rm, m);
    }
    float mm = fmaxf(rm[0], rm[1]);
    u32 mmb = __float_as_uint(mm);
    // thread-local index of first (lowest-j) point attaining mm
    u32 jinv = 0u;
    #pragma unroll
    for (int p=7;p>=0;p--){
      if (__float_as_uint(md[p][1])==mmb) jinv = invb-(u32)(2*p+1);
      if (__float_as_uint(md[p][0])==mmb) jinv = invb-(u32)(2*p);
    }
    // wave reduce: value max, then min global index among matching lanes
    u32 kred = wave_max_u32(mmb);                         // lane63 = wave max bits
    u32 mvb  = (u32)__builtin_amdgcn_readlane((int)kred, 63);
    u32 cand = (mmb==mvb) ? jinv : 0u;
    cand = wave_max_u32(cand);                            // lane63 = max(invb-j) = min idx
    int par = step & 1;
    if (lane==63) skey[par][wv] = ((u64)mvb<<32) | (u64)cand;
    __syncthreads();                     // single barrier per step
    u64 a0=skey[par][0],a1=skey[par][1],a2=skey[par][2],a3=skey[par][3];
    u64 a4=skey[par][4],a5=skey[par][5],a6=skey[par][6],a7=skey[par][7];
    a0=(a1>a0)?a1:a0; a2=(a3>a2)?a3:a2; a4=(a5>a4)?a5:a4; a6=(a7>a6)?a7:a6;
    a0=(a2>a0)?a2:a0; a4=(a6>a4)?a6:a4;
    a0=(a4>a0)?a4:a0;
    far = (int)(0xFFFFFFFFu - (u32)(a0 & 0xFFFFFFFFull));
  }
  // f32 output: exact raw coordinates of selected points
  for (int i=tid;i<M_;i+=512){
    int id = sidx[i];
    float x=sx[id], y=sy[id], z=sz[id];
    size_t o=(size_t)(b*M_+i)*3;
    nxyz[o]=x; nxyz[o+1]=y; nxyz[o+2]=z;
    out0[o]=x; out0[o+1]=y; out0[o+2]=z;
  }
}

// ---------------------------------------------------------------- ball query
// u64-key DPP min ladder selection (R2, kept: part of the -200us rest-of-pipe win)
#define BQCAP 512
__global__ __launch_bounds__(512) void k_bq(const float* __restrict__ xyz, const float* __restrict__ nxyz,
                                            int* __restrict__ knn)
{
  __shared__ float4 sP[N_];
  __shared__ float candd[8][BQCAP];
  __shared__ u16  candi[8][BQCAP];
  int tid=threadIdx.x;
  int cid0 = blockIdx.x*8;
  int b = cid0 >> 11;
  const float* xp = xyz + (size_t)b*N_*3;
  for (int i=tid;i<N_;i+=512){
    float x=xp[i*3], y=xp[i*3+1], z=xp[i*3+2];
    float x2 = __fmul_rn(x,x);
    x2 = __fadd_rn(x2, __fmul_rn(y,y));
    x2 = __fadd_rn(x2, __fmul_rn(z,z));
    sP[i]=make_float4(x,y,z,x2);
  }
  __syncthreads();
  int w=tid>>6, lane=tid&63;
  int cid = cid0 + w;
  float cx=nxyz[(size_t)cid*3], cy=nxyz[(size_t)cid*3+1], cz=nxyz[(size_t)cid*3+2];
  float c2 = __fmul_rn(cx,cx);
  c2 = __fadd_rn(c2, __fmul_rn(cy,cy));
  c2 = __fadd_rn(c2, __fmul_rn(cz,cz));
  int cnt=0;
  for (int i0=0;i0<N_;i0+=64){
    int i=i0+lane;
    float4 p=sP[i];
    float dot = __fmul_rn(cx,p.x);
    dot = __fadd_rn(dot, __fmul_rn(cy,p.y));
    dot = __fadd_rn(dot, __fmul_rn(cz,p.z));
    float d2 = __fsub_rn(__fadd_rn(c2,p.w), __fmul_rn(2.0f,dot));
    float d = sqrtf(fmaxf(d2,0.f));
    bool in = (d <= 0.4f);
    u64 msk = __ballot(in);
    int pos = cnt + __popcll(msk & ((1ull<<lane)-1ull));
    if (in && pos<BQCAP){ candd[w][pos]=d; candi[w][pos]=(u16)i; }
    cnt += __popcll(msk);
  }
  int R = cnt<BQCAP ? cnt : BQCAP;
  int* kout = knn + (size_t)cid*NS_;
  if (R >= NS_){
    for (int s=0;s<NS_;s++){
      u64 kb = ~0ull;                    // min identity
      for (int j=lane;j<R;j+=64){
        float v=candd[w][j];
        u64 k = ((u64)__float_as_uint(v)<<32) | (u64)(u32)j;
        kb = (k<kb)?k:kb;
      }
      u64 inv = wave_max_key(~kb);       // min via complemented max
      if (lane==63){
        u64 kw = ~inv;
        int bpp = (int)(u32)(kw & 0xFFFFFFFFull);
        kout[s]=candi[w][bpp];
        candd[w][bpp]=3e38f;             // same-wave DS in-order: visible next pass
      }
    }
  } else {
    if (lane<R) kout[lane]=candi[w][lane];
    int need = NS_-R, slot = R;
    for (int i0=0; i0<N_ && need>0; i0+=64){
      int i=i0+lane;
      float4 p=sP[i];
      float dot = __fmul_rn(cx,p.x);
      dot = __fadd_rn(dot, __fmul_rn(cy,p.y));
      dot = __fadd_rn(dot, __fmul_rn(cz,p.z));
      float d2 = __fsub_rn(__fadd_rn(c2,p.w), __fmul_rn(2.0f,dot));
      float d = sqrtf(fmaxf(d2,0.f));
      bool in = (d <= 0.4f);
      u64 mm = __ballot(!in);
      while (mm && need>0){
        int bpos = __ffsll((long long)mm)-1;
        if (lane==0) kout[slot] = i0+bpos;
        slot++; need--;
        mm &= mm-1;
      }
    }
  }
}

// ---------------------------------------------------------------- layer 0 (gather+concat fused)
__global__ __launch_bounds__(256) void k_mm0(const float* __restrict__ xyz, const u16* __restrict__ featT,
                                             const int* __restrict__ knn, const float* __restrict__ nxyz,
                                             const float* __restrict__ Wt0, const float* __restrict__ biasf,
                                             u16* __restrict__ Y0)
{
  __shared__ u16 Xs[256*70];
  __shared__ float Wl[67*64];
  int tid=threadIdx.x;
  for (int i=tid;i<67*64;i+=256) Wl[i]=Wt0[i];
  int base = blockIdx.x*256;
  {
    int row = base + tid;
    int bm  = row >> 5;
    int b   = row >> 16;
    int n   = knn[row];
    const float* cp = nxyz + (size_t)bm*3;
    const float* xp = xyz + ((size_t)b*N_ + n)*3;
    u16* xr = &Xs[tid*70];
    xr[0]=f2bf(xp[0]-cp[0]);
    xr[1]=f2bf(xp[1]-cp[1]);
    xr[2]=f2bf(xp[2]-cp[2]);
    const uint4* fp = (const uint4*)(featT + ((size_t)b*N_ + n)*CIN_);
    #pragma unroll
    for (int i=0;i<8;i++){
      uint4 v=fp[i];
      u16* d = xr + 3 + i*8;
      d[0]=(u16)(v.x&0xFFFFu); d[1]=(u16)(v.x>>16);
      d[2]=(u16)(v.y&0xFFFFu); d[3]=(u16)(v.y>>16);
      d[4]=(u16)(v.z&0xFFFFu); d[5]=(u16)(v.z>>16);
      d[6]=(u16)(v.w&0xFFFFu); d[7]=(u16)(v.w>>16);
    }
  }
  __syncthreads();
  int g=tid>>7, rt=tid&127;
  float acc0[32], acc1[32];
  #pragma unroll
  for (int j=0;j<32;j++){ acc0[j]=0.f; acc1[j]=0.f; }
  const u16* xa=&Xs[rt*70];
  const u16* xb=&Xs[(rt+128)*70];
  for (int c=0;c<67;c++){
    float a=bf2f(xa[c]);
    float bx=bf2f(xb[c]);
    const float4* wr=(const float4*)&Wl[c*64 + g*32];
    #pragma unroll
    for (int o=0;o<8;o++){
      float4 wv=wr[o];
      acc0[o*4+0]+=a*wv.x;  acc0[o*4+1]+=a*wv.y;  acc0[o*4+2]+=a*wv.z;  acc0[o*4+3]+=a*wv.w;
      acc1[o*4+0]+=bx*wv.x; acc1[o*4+1]+=bx*wv.y; acc1[o*4+2]+=bx*wv.z; acc1[o*4+3]+=bx*wv.w;
    }
  }
  float bb[32];
  #pragma unroll
  for (int j=0;j<32;j++) bb[j]=biasf[g*32+j];
  u16* y0p = Y0 + ((size_t)(base+rt))*64 + g*32;
  u16* y1p = Y0 + ((size_t)(base+rt+128))*64 + g*32;
  #pragma unroll
  for (int j=0;j<32;j++){
    y0p[j]=f2bf(acc0[j]+bb[j]);
    y1p[j]=f2bf(acc1[j]+bb[j]);
  }
}

// ---------------------------------------------------------------- channel stats (sum, sumsq)
template<int C>
__global__ __launch_bounds__(256) void k_stats(const u16* __restrict__ Y, float* __restrict__ statsOut)
{
  __shared__ float sred[4][128];
  int tid=threadIdx.x;
  int c0=(tid&7)*8;          // 8 channels per thread
  int rg=tid>>3;             // 32 row-groups per block
  float s[8], ss[8];
  #pragma unroll
  for (int k=0;k<8;k++){ s[k]=0.f; ss[k]=0.f; }
  for (size_t r=(size_t)blockIdx.x*32+rg; r<ROWS_; r+=(size_t)gridDim.x*32){
    uint4 v=*(const uint4*)&Y[r*64+c0];
    u32 a[4]={v.x,v.y,v.z,v.w};
    #pragma unroll
    for (int q=0;q<4;q++){
      float lo=bf2f((u16)(a[q]&0xFFFFu));
      float hi=bf2f((u16)(a[q]>>16));
      s[q*2]+=lo;   ss[q*2]+=lo*lo;
      s[q*2+1]+=hi; ss[q*2+1]+=hi*hi;
    }
  }
  #pragma unroll
  for (int off=32; off>=8; off>>=1){
    #pragma unroll
    for (int k=0;k<8;k++){
      s[k]+=__shfl_down(s[k],off);
      ss[k]+=__shfl_down(ss[k],off);
    }
  }
  int lane=tid&63, wv=tid>>6;
  if (lane<8){
    #pragma unroll
    for (int k=0;k<8;k++){
      int ch=lane*8+k;
      sred[wv][ch]=s[k];
      sred[wv][64+ch]=ss[k];
    }
  }
  __syncthreads();
  if (tid<128){
    float a=sred[0][tid]+sred[1][tid]+sred[2][tid]+sred[3][tid];
    int ch=tid&63, which=tid>>6;
    atomicAdd(&statsOut[ch*2+which], a);
  }
}

// ---------------------------------------------------------------- layer 1 (bn0+relu fused into stage; in-place)
__global__ __launch_bounds__(256) void k_mm1(u16* __restrict__ Y, const float* __restrict__ Wt1,
                                             const float* __restrict__ bias1, const float* __restrict__ gf0,
                                             const float* __restrict__ btf0, const float* __restrict__ stats0)
{
  __shared__ u16 Xs[256*66];
  __shared__ float Wl[64*64];
  __shared__ float sc[64], sh[64];
  int tid=threadIdx.x;
  if (tid<64){
    float mu = stats0[tid*2]*INV_ROWS;
    float var= stats0[tid*2+1]*INV_ROWS - mu*mu;
    float rs = 1.0f/sqrtf(var+EPSF);
    float s  = rs*gf0[tid];
    sc[tid]=s; sh[tid]=btf0[tid]-mu*s;
  }
  for (int i=tid;i<64*64;i+=256) Wl[i]=Wt1[i];
  __syncthreads();
  size_t base=(size_t)blockIdx.x*256;
  for (int i=tid;i<2048;i+=256){
    int rl=i>>3, c0=(i&7)*8;
    uint4 v=*(const uint4*)(Y + (base+rl)*64 + c0);
    u32 arr[4]={v.x,v.y,v.z,v.w};
    u16* d=&Xs[rl*66+c0];
    #pragma unroll
    for (int q=0;q<4;q++){
      int cc=c0+q*2;
      float lo=bf2f((u16)(arr[q]&0xFFFFu));
      float hi=bf2f((u16)(arr[q]>>16));
      lo=fmaxf(0.f, lo*sc[cc]+sh[cc]);
      hi=fmaxf(0.f, hi*sc[cc+1]+sh[cc+1]);
      d[q*2]=f2bf(lo); d[q*2+1]=f2bf(hi);
    }
  }
  __syncthreads();
  int g=tid>>7, rt=tid&127;
  float acc0[32], acc1[32];
  #pragma unroll
  for (int j=0;j<32;j++){ acc0[j]=0.f; acc1[j]=0.f; }
  const u16* xa=&Xs[rt*66];
  const u16* xb=&Xs[(rt+128)*66];
  for (int c=0;c<64;c++){
    float a=bf2f(xa[c]);
    float bx=bf2f(xb[c]);
    const float4* wr=(const float4*)&Wl[c*64 + g*32];
    #pragma unroll
    for (int o=0;o<8;o++){
      float4 wv=wr[o];
      acc0[o*4+0]+=a*wv.x;  acc0[o*4+1]+=a*wv.y;  acc0[o*4+2]+=a*wv.z;  acc0[o*4+3]+=a*wv.w;
      acc1[o*4+0]+=bx*wv.x; acc1[o*4+1]+=bx*wv.y; acc1[o*4+2]+=bx*wv.z; acc1[o*4+3]+=bx*wv.w;
    }
  }
  float bb[32];
  #pragma unroll
  for (int j=0;j<32;j++) bb[j]=bias1[g*32+j];
  u16* y0p = Y + (base+rt)*64 + g*32;
  u16* y1p = Y + (base+rt+128)*64 + g*32;
  #pragma unroll
  for (int j=0;j<32;j++){
    y0p[j]=f2bf(acc0[j]+bb[j]);
    y1p[j]=f2bf(acc1[j]+bb[j]);
  }
}

// ---------------------------------------------------------------- layer 2: stats + RAW maxpool (Y2 never stored)
__global__ __launch_bounds__(256) void k_mm2a(const u16* __restrict__ Y1, const float* __restrict__ Wt2,
                                              const float* __restrict__ bias2, const float* __restrict__ gf1,
                                              const float* __restrict__ btf1, const float* __restrict__ stats1,
                                              float* __restrict__ stats2, float* __restrict__ out1)
{
  __shared__ u16 Xs[128*66];
  __shared__ float Wl[64*128];
  __shared__ float sc[64], sh[64];
  __shared__ float res[4][128];
  int tid=threadIdx.x;
  if (tid<64){
    float mu = stats1[tid*2]*INV_ROWS;
    float var= stats1[tid*2+1]*INV_ROWS - mu*mu;
    float rs = 1.0f/sqrtf(var+EPSF);
    float s  = rs*gf1[tid];
    sc[tid]=s; sh[tid]=btf1[tid]-mu*s;
  }
  for (int i=tid;i<64*128;i+=256) Wl[i]=Wt2[i];
  int g=tid>>6, rt=tid&63;
  float bb[32];
  #pragma unroll
  for (int j=0;j<32;j++) bb[j]=bias2[g*32+j];
  float sSum[32], sSq[32];
  #pragma unroll
  for (int j=0;j<32;j++){ sSum[j]=0.f; sSq[j]=0.f; }
  __syncthreads();
  for (int tile=blockIdx.x; tile<4096; tile+=gridDim.x){
    size_t base=(size_t)tile*128;
    for (int i=tid;i<1024;i+=256){
      int rl=i>>3, c0=(i&7)*8;
      uint4 v=*(const uint4*)(Y1 + (base+rl)*64 + c0);
      u32 arr[4]={v.x,v.y,v.z,v.w};
      u16* d=&Xs[rl*66+c0];
      #pragma unroll
      for (int q=0;q<4;q++){
        int cc=c0+q*2;
        float lo=bf2f((u16)(arr[q]&0xFFFFu));
        float hi=bf2f((u16)(arr[q]>>16));
        lo=fmaxf(0.f, lo*sc[cc]+sh[cc]);
        hi=fmaxf(0.f, hi*sc[cc+1]+sh[cc+1]);
        d[q*2]=f2bf(lo); d[q*2+1]=f2bf(hi);
      }
    }
    __syncthreads();
    float acc0[32], acc1[32];
    #pragma unroll
    for (int j=0;j<32;j++){ acc0[j]=0.f; acc1[j]=0.f; }
    const u16* xa=&Xs[rt*66];
    const u16* xb=&Xs[(rt+64)*66];
    for (int c=0;c<64;c++){
      float a=bf2f(xa[c]);
      float bx=bf2f(xb[c]);
      const float4* wr=(const float4*)&Wl[c*128 + g*32];
      #pragma unroll
      for (int o=0;o<8;o++){
        float4 wv=wr[o];
        acc0[o*4+0]+=a*wv.x;  acc0[o*4+1]+=a*wv.y;  acc0[o*4+2]+=a*wv.z;  acc0[o*4+3]+=a*wv.w;
        acc1[o*4+0]+=bx*wv.x; acc1[o*4+1]+=bx*wv.y; acc1[o*4+2]+=bx*wv.z; acc1[o*4+3]+=bx*wv.w;
      }
    }
    #pragma unroll
    for (int j=0;j<32;j++){
      float y0=acc0[j]+bb[j], y1=acc1[j]+bb[j];
      sSum[j]+=y0+y1;
      sSq[j] +=y0*y0+y1*y1;
      float a=y0, b2=y1;
      #pragma unroll
      for (int off=16;off>0;off>>=1){
        a = fmaxf(a, __shfl_down(a, off, 32));
        b2= fmaxf(b2,__shfl_down(b2,off, 32));
      }
      if ((rt&31)==0){
        int o=g*32+j;
        res[rt>>5][o]     = a;
        res[2+(rt>>5)][o] = b2;
      }
    }
    __syncthreads();
    int bm0 = tile*4;
    for (int e=tid;e<512;e+=256){
      int gr=e>>7, o=e&127;
      int bm=bm0+gr; int bi=bm>>11, m=bm&2047;
      out1[((size_t)bi*128+o)*M_ + m] = res[gr][o];
    }
    __syncthreads();
  }
  #pragma unroll
  for (int off=32;off>0;off>>=1){
    #pragma unroll
    for (int j=0;j<32;j++){
      sSum[j]+=__shfl_down(sSum[j],off);
      sSq[j] +=__shfl_down(sSq[j],off);
    }
  }
  if (rt==0){
    #pragma unroll
    for (int j=0;j<32;j++){
      atomicAdd(&stats2[(g*32+j)*2],  sSum[j]);
      atomicAdd(&stats2[(g*32+j)*2+1],sSq[j]);
    }
  }
}

// ---------------------------------------------------------------- final pool: in-place BN2+ReLU on raw maxes
__global__ __launch_bounds__(256) void k_pool(float* __restrict__ out1, const float* __restrict__ stats2,
                                              const float* __restrict__ gf2, const float* __restrict__ btf2)
{
  int idx = blockIdx.x*256 + threadIdx.x;     // 8*128*2048 = 2097152 elements
  int o = (idx >> 11) & 127;
  float mu = stats2[o*2]*INV_ROWS;
  float var= stats2[o*2+1]*INV_ROWS - mu*mu;
  float rs = 1.0f/sqrtf(var+EPSF);
  float s  = rs*gf2[o];
  float sh = btf2[o]-mu*s;
  out1[idx] = fmaxf(0.f, out1[idx]*s + sh);
}

// ---------------------------------------------------------------- launch
extern "C" void kernel_launch(void* const* d_in, const int* in_sizes, int n_in,
                              void* d_out, int out_size, void* d_ws, size_t ws_size,
                              hipStream_t stream)
{
  (void)in_sizes; (void)n_in; (void)out_size; (void)ws_size;
  const float* xyz =(const float*)d_in[0];
  const float* feat=(const float*)d_in[1];
  const float* w0=(const float*)d_in[2],  *b0=(const float*)d_in[3],  *g0=(const float*)d_in[4],  *bt0=(const float*)d_in[5];
  const float* w1=(const float*)d_in[6],  *b1=(const float*)d_in[7],  *g1=(const float*)d_in[8],  *bt1=(const float*)d_in[9];
  const float* w2=(const float*)d_in[10], *b2=(const float*)d_in[11], *g2=(const float*)d_in[12], *bt2=(const float*)d_in[13];
  float* out0=(float*)d_out;
  float* out1=out0 + (size_t)B_*M_*3;

  char* ws=(char*)d_ws;
  float* nxyz =(float*)(ws);              // 196608 B
  int*   knn  =(int*)  (ws + 262144);     // 2097152
  float* Wt0  =(float*)(ws + 2359296);    // 17408
  float* Wt1  =(float*)(ws + 2376704);    // 16384
  float* Wt2  =(float*)(ws + 2393088);    // 32768
  float* biasf=(float*)(ws + 2425856);    // 1536
  float* gfp  =(float*)(ws + 2427392);    // 1536
  float* btfp =(float*)(ws + 2428928);    // 1536
  float* stats=(float*)(ws + 2430464);    // 3072
  u16*   featT=(u16*)  (ws + 2433536);    // 8388608
  u16*   Y0   =(u16*)  (ws + 10822144);   // 67108864  (total ~78 MB)

  k_prep<<<1,256,0,stream>>>(w0,b0,g0,bt0,w1,b1,g1,bt1,w2,b2,g2,bt2,Wt0,Wt1,Wt2,biasf,gfp,btfp,stats);
  k_tr<<<dim3(128,8),256,0,stream>>>(feat, featT);
  k_fps<<<B_,512,0,stream>>>(xyz, nxyz, out0);
  k_bq<<<2048,512,0,stream>>>(xyz, nxyz, knn);
  k_mm0<<<2048,256,0,stream>>>(xyz, featT, knn, nxyz, Wt0, biasf+0, Y0);
  k_stats<64><<<128,256,0,stream>>>(Y0, stats+0);
  k_mm1<<<2048,256,0,stream>>>(Y0, Wt1, biasf+128, gfp+0, btfp+0, stats+0);
  k_stats<64><<<128,256,0,stream>>>(Y0, stats+256);
  k_mm2a<<<512,256,0,stream>>>(Y0, Wt2, biasf+256, gfp+128, btfp+128, stats+256, stats+512, out1);
  k_pool<<<8192,256,0,stream>>>(out1, stats+512, gfp+256, btfp+256);
}

// Round 5
// 2667.662 us; speedup vs baseline: 1.2388x; 1.0390x over previous
//
#include <hip/hip_runtime.h>
#include <hip/hip_bf16.h>
#include <stdint.h>

typedef unsigned short u16;
typedef unsigned int   u32;
typedef unsigned long long u64;
typedef float v2f __attribute__((ext_vector_type(2)));
typedef __attribute__((ext_vector_type(8))) short bf16x8;
typedef __attribute__((ext_vector_type(4))) float f32x4;

#define B_    8
#define N_    8192
#define M_    2048
#define NS_   32
#define CIN_  64
#define ROWS_ (B_*M_*NS_)          // 524288
#define BIGF  1e10f
#define EPSF  1e-5f
#define INV_ROWS (1.0f/524288.0f)  // 2^-19, exact

__device__ __forceinline__ u16 f2bf(float f){
  u32 x=__float_as_uint(f);
  return (u16)((x + 0x7FFFu + ((x>>16)&1u))>>16);   // RNE
}
__device__ __forceinline__ float bf2f(u16 u){ return __uint_as_float(((u32)u)<<16); }

// DPP full-wave max of non-negative u64 keys; result lands in lane 63.
// bound_ctrl 0-fill is the identity for max of non-negative keys.
__device__ __forceinline__ u64 wave_max_key(u64 k){
#define DPP_LVL(CTRL) { \
    u32 lo_=(u32)__builtin_amdgcn_update_dpp(0,(int)(u32)k,(CTRL),0xF,0xF,true); \
    u32 hi_=(u32)__builtin_amdgcn_update_dpp(0,(int)(u32)(k>>32),(CTRL),0xF,0xF,true); \
    u64 o_=((u64)hi_<<32)|(u64)lo_; \
    k=(o_>k)?o_:k; }
  DPP_LVL(0x111)  // row_shr:1
  DPP_LVL(0x112)  // row_shr:2
  DPP_LVL(0x114)  // row_shr:4
  DPP_LVL(0x118)  // row_shr:8
  DPP_LVL(0x142)  // row_bcast:15
  DPP_LVL(0x143)  // row_bcast:31  -> lane 63 holds wave max
#undef DPP_LVL
  return k;
}

// ---------------------------------------------------------------- prep (fp32 weights in)
// Adds: B-operand MFMA fragment layout for W1, split-precision bf16 (hi+lo).
// B-frag (16x16x32): col = tn*16 + (lane&15), k = k0*32 + (lane>>4)*8 + e.
__global__ __launch_bounds__(256) void k_prep(
    const float* w0,const float* b0,const float* g0,const float* bt0,
    const float* w1,const float* b1,const float* g1,const float* bt1,
    const float* w2,const float* b2,const float* g2,const float* bt2,
    float* Wt0,float* Wt1,float* Wt2,
    float* biasf,float* gf,float* btf,float* stats,
    u16* Wb1h, u16* Wb1l)
{
  int tid=threadIdx.x;
  for (int i=tid;i<768;i+=256) stats[i]=0.f;
  for (int i=tid;i<67*64;i+=256){ int c=i>>6,o=i&63;  Wt0[c*64+o]=w0[o*67+c]; }
  for (int i=tid;i<64*64;i+=256){ int c=i>>6,o=i&63;  Wt1[c*64+o]=w1[o*64+c]; }
  for (int i=tid;i<64*128;i+=256){int c=i>>7,o=i&127; Wt2[c*128+o]=w2[o*64+c]; }
  // W1 MFMA B-fragments, split precision: w = bf16(hi) + bf16(lo) + O(2^-16 rel)
  for (int i=tid;i<4096;i+=256){
    int e=i&7, lane=(i>>3)&63, k0=(i>>9)&1, tn=i>>10;
    int col = tn*16 + (lane&15);
    int k   = k0*32 + ((lane>>4)&3)*8 + e;
    float v = w1[col*64 + k];
    u16 hib = f2bf(v);
    float lo = v - bf2f(hib);
    Wb1h[i] = hib;
    Wb1l[i] = f2bf(lo);
  }
  if (tid<64){
    biasf[0*128+tid]=b0[tid]; gf[0*128+tid]=g0[tid]; btf[0*128+tid]=bt0[tid];
    biasf[1*128+tid]=b1[tid]; gf[1*128+tid]=g1[tid]; btf[1*128+tid]=bt1[tid];
  }
  if (tid<128){
    biasf[2*128+tid]=b2[tid]; gf[2*128+tid]=g2[tid]; btf[2*128+tid]=bt2[tid];
  }
}

// ------------------------------------------------------- feature transpose
__global__ __launch_bounds__(256) void k_tr(const float* __restrict__ feats, u16* __restrict__ featT)
{
  __shared__ float t[64][65];
  int bb=blockIdx.y, n0=blockIdx.x*64, tid=threadIdx.x;
  int a=tid&63, q=tid>>6;
  const float* fp = feats + (size_t)bb*CIN_*N_;
  #pragma unroll
  for (int s=0;s<16;s++){ int c=q*16+s; t[c][a]=fp[(size_t)c*N_ + n0 + a]; }
  __syncthreads();
  u16* op = featT + (size_t)bb*N_*CIN_;
  #pragma unroll
  for (int s=0;s<16;s++){ int n=q*16+s; op[(size_t)(n0+n)*CIN_ + a] = f2bf(t[a][n]); }
}

// ---------------------------------------------------------------- FPS
// VERBATIM revert to the R1 kernel (measured best: 1735us). 512 thr, 16 pts/thread,
// PRE-update emission, v2f C arithmetic (contract off), in-loop packed u64 keys,
// single u64 DPP ladder, parity skey[2][8] publish + 8-load tree merge.
__global__ __launch_bounds__(512) void k_fps(const float* __restrict__ xyz,
                                             float* __restrict__ nxyz, float* __restrict__ out0)
{
#pragma clang fp contract(off)
  __shared__ float sx[N_], sy[N_], sz[N_];
  __shared__ int sidx[M_];
  __shared__ u64 skey[2][8];
  int b=blockIdx.x, tid=threadIdx.x;
  const float* xp = xyz + (size_t)b*N_*3;
  for (int i=tid;i<N_;i+=512){ sx[i]=xp[i*3]; sy[i]=xp[i*3+1]; sz[i]=xp[i*3+2]; }
  __syncthreads();
  v2f px[8],py[8],pz[8],md[8];
  int base = tid*16;
  #pragma unroll
  for (int p=0;p<8;p++){
    px[p]=*(const v2f*)&sx[base+2*p];
    py[p]=*(const v2f*)&sy[base+2*p];
    pz[p]=*(const v2f*)&sz[base+2*p];
    v2f m0; m0[0]=BIGF; m0[1]=BIGF; md[p]=m0;
  }
  u32 invb = 0xFFFFFFFFu - (u32)base;
  int far=0;
  int lane=tid&63, wv=tid>>6;
  for (int step=0; step<M_; step++){
    if (tid==0) sidx[step]=far;          // PRE-update emission
    float cxs=sx[far], cys=sy[far], czs=sz[far];
    v2f cx; cx[0]=cxs; cx[1]=cxs;
    v2f cy; cy[0]=cys; cy[1]=cys;
    v2f cz; cz[0]=czs; cz[1]=czs;
    u64 kb=0;
    #pragma unroll
    for (int p=0;p<8;p++){
      v2f dx=px[p]-cx, dy=py[p]-cy, dz=pz[p]-cz;
      v2f d=(dx*dx+dy*dy)+dz*dz;         // contract off: same assoc as ((xx+yy)+zz)
      v2f m=__builtin_elementwise_min(md[p],d);
      md[p]=m;
      u64 k0=((u64)__float_as_uint(m[0])<<32)|(u64)(invb-(u32)(2*p));
      u64 k1=((u64)__float_as_uint(m[1])<<32)|(u64)(invb-(u32)(2*p+1));
      u64 kp=(k1>k0)?k1:k0;              // equal dist -> k0 (lower idx) wins: larger ~idx
      kb=(kp>kb)?kp:kb;
    }
    kb = wave_max_key(kb);
    int par = step & 1;
    if (lane==63) skey[par][wv]=kb;
    __syncthreads();                     // single barrier per step
    u64 a0=skey[par][0],a1=skey[par][1],a2=skey[par][2],a3=skey[par][3];
    u64 a4=skey[par][4],a5=skey[par][5],a6=skey[par][6],a7=skey[par][7];
    a0=(a1>a0)?a1:a0; a2=(a3>a2)?a3:a2; a4=(a5>a4)?a5:a4; a6=(a7>a6)?a7:a6;
    a0=(a2>a0)?a2:a0; a4=(a6>a4)?a6:a4;
    a0=(a4>a0)?a4:a0;
    far = (int)(0xFFFFFFFFu - (u32)(a0 & 0xFFFFFFFFull));
  }
  // f32 output: exact raw coordinates of selected points
  for (int i=tid;i<M_;i+=512){
    int id = sidx[i];
    float x=sx[id], y=sy[id], z=sz[id];
    size_t o=(size_t)(b*M_+i)*3;
    nxyz[o]=x; nxyz[o+1]=y; nxyz[o+2]=z;
    out0[o]=x; out0[o+1]=y; out0[o+2]=z;
  }
}

// ---------------------------------------------------------------- ball query
#define BQCAP 512
__global__ __launch_bounds__(512) void k_bq(const float* __restrict__ xyz, const float* __restrict__ nxyz,
                                            int* __restrict__ knn)
{
  __shared__ float4 sP[N_];
  __shared__ float candd[8][BQCAP];
  __shared__ u16  candi[8][BQCAP];
  int tid=threadIdx.x;
  int cid0 = blockIdx.x*8;
  int b = cid0 >> 11;
  const float* xp = xyz + (size_t)b*N_*3;
  for (int i=tid;i<N_;i+=512){
    float x=xp[i*3], y=xp[i*3+1], z=xp[i*3+2];
    float x2 = __fmul_rn(x,x);
    x2 = __fadd_rn(x2, __fmul_rn(y,y));
    x2 = __fadd_rn(x2, __fmul_rn(z,z));
    sP[i]=make_float4(x,y,z,x2);
  }
  __syncthreads();
  int w=tid>>6, lane=tid&63;
  int cid = cid0 + w;
  float cx=nxyz[(size_t)cid*3], cy=nxyz[(size_t)cid*3+1], cz=nxyz[(size_t)cid*3+2];
  float c2 = __fmul_rn(cx,cx);
  c2 = __fadd_rn(c2, __fmul_rn(cy,cy));
  c2 = __fadd_rn(c2, __fmul_rn(cz,cz));
  int cnt=0;
  for (int i0=0;i0<N_;i0+=64){
    int i=i0+lane;
    float4 p=sP[i];
    float dot = __fmul_rn(cx,p.x);
    dot = __fadd_rn(dot, __fmul_rn(cy,p.y));
    dot = __fadd_rn(dot, __fmul_rn(cz,p.z));
    float d2 = __fsub_rn(__fadd_rn(c2,p.w), __fmul_rn(2.0f,dot));
    float d = sqrtf(fmaxf(d2,0.f));
    bool in = (d <= 0.4f);
    u64 msk = __ballot(in);
    int pos = cnt + __popcll(msk & ((1ull<<lane)-1ull));
    if (in && pos<BQCAP){ candd[w][pos]=d; candi[w][pos]=(u16)i; }
    cnt += __popcll(msk);
  }
  int R = cnt<BQCAP ? cnt : BQCAP;
  int* kout = knn + (size_t)cid*NS_;
  if (R >= NS_){
    for (int s=0;s<NS_;s++){
      u64 kb = ~0ull;                    // min identity
      for (int j=lane;j<R;j+=64){
        float v=candd[w][j];
        u64 k = ((u64)__float_as_uint(v)<<32) | (u64)(u32)j;
        kb = (k<kb)?k:kb;
      }
      u64 inv = wave_max_key(~kb);       // min via complemented max
      if (lane==63){
        u64 kw = ~inv;
        int bpp = (int)(u32)(kw & 0xFFFFFFFFull);
        kout[s]=candi[w][bpp];
        candd[w][bpp]=3e38f;             // same-wave DS in-order: visible next pass
      }
    }
  } else {
    if (lane<R) kout[lane]=candi[w][lane];
    int need = NS_-R, slot = R;
    for (int i0=0; i0<N_ && need>0; i0+=64){
      int i=i0+lane;
      float4 p=sP[i];
      float dot = __fmul_rn(cx,p.x);
      dot = __fadd_rn(dot, __fmul_rn(cy,p.y));
      dot = __fadd_rn(dot, __fmul_rn(cz,p.z));
      float d2 = __fsub_rn(__fadd_rn(c2,p.w), __fmul_rn(2.0f,dot));
      float d = sqrtf(fmaxf(d2,0.f));
      bool in = (d <= 0.4f);
      u64 mm = __ballot(!in);
      while (mm && need>0){
        int bpos = __ffsll((long long)mm)-1;
        if (lane==0) kout[slot] = i0+bpos;
        slot++; need--;
        mm &= mm-1;
      }
    }
  }
}

// ---------------------------------------------------------------- layer 0 (gather+concat fused)
__global__ __launch_bounds__(256) void k_mm0(const float* __restrict__ xyz, const u16* __restrict__ featT,
                                             const int* __restrict__ knn, const float* __restrict__ nxyz,
                                             const float* __restrict__ Wt0, const float* __restrict__ biasf,
                                             u16* __restrict__ Y0)
{
  __shared__ u16 Xs[256*70];
  __shared__ float Wl[67*64];
  int tid=threadIdx.x;
  for (int i=tid;i<67*64;i+=256) Wl[i]=Wt0[i];
  int base = blockIdx.x*256;
  {
    int row = base + tid;
    int bm  = row >> 5;
    int b   = row >> 16;
    int n   = knn[row];
    const float* cp = nxyz + (size_t)bm*3;
    const float* xp = xyz + ((size_t)b*N_ + n)*3;
    u16* xr = &Xs[tid*70];
    xr[0]=f2bf(xp[0]-cp[0]);
    xr[1]=f2bf(xp[1]-cp[1]);
    xr[2]=f2bf(xp[2]-cp[2]);
    const uint4* fp = (const uint4*)(featT + ((size_t)b*N_ + n)*CIN_);
    #pragma unroll
    for (int i=0;i<8;i++){
      uint4 v=fp[i];
      u16* d = xr + 3 + i*8;
      d[0]=(u16)(v.x&0xFFFFu); d[1]=(u16)(v.x>>16);
      d[2]=(u16)(v.y&0xFFFFu); d[3]=(u16)(v.y>>16);
      d[4]=(u16)(v.z&0xFFFFu); d[5]=(u16)(v.z>>16);
      d[6]=(u16)(v.w&0xFFFFu); d[7]=(u16)(v.w>>16);
    }
  }
  __syncthreads();
  int g=tid>>7, rt=tid&127;
  float acc0[32], acc1[32];
  #pragma unroll
  for (int j=0;j<32;j++){ acc0[j]=0.f; acc1[j]=0.f; }
  const u16* xa=&Xs[rt*70];
  const u16* xb=&Xs[(rt+128)*70];
  for (int c=0;c<67;c++){
    float a=bf2f(xa[c]);
    float bx=bf2f(xb[c]);
    const float4* wr=(const float4*)&Wl[c*64 + g*32];
    #pragma unroll
    for (int o=0;o<8;o++){
      float4 wv=wr[o];
      acc0[o*4+0]+=a*wv.x;  acc0[o*4+1]+=a*wv.y;  acc0[o*4+2]+=a*wv.z;  acc0[o*4+3]+=a*wv.w;
      acc1[o*4+0]+=bx*wv.x; acc1[o*4+1]+=bx*wv.y; acc1[o*4+2]+=bx*wv.z; acc1[o*4+3]+=bx*wv.w;
    }
  }
  float bb[32];
  #pragma unroll
  for (int j=0;j<32;j++) bb[j]=biasf[g*32+j];
  u16* y0p = Y0 + ((size_t)(base+rt))*64 + g*32;
  u16* y1p = Y0 + ((size_t)(base+rt+128))*64 + g*32;
  #pragma unroll
  for (int j=0;j<32;j++){
    y0p[j]=f2bf(acc0[j]+bb[j]);
    y1p[j]=f2bf(acc1[j]+bb[j]);
  }
}

// ---------------------------------------------------------------- channel stats (sum, sumsq)
template<int C>
__global__ __launch_bounds__(256) void k_stats(const u16* __restrict__ Y, float* __restrict__ statsOut)
{
  __shared__ float sred[4][128];
  int tid=threadIdx.x;
  int c0=(tid&7)*8;          // 8 channels per thread
  int rg=tid>>3;             // 32 row-groups per block
  float s[8], ss[8];
  #pragma unroll
  for (int k=0;k<8;k++){ s[k]=0.f; ss[k]=0.f; }
  for (size_t r=(size_t)blockIdx.x*32+rg; r<ROWS_; r+=(size_t)gridDim.x*32){
    uint4 v=*(const uint4*)&Y[r*64+c0];
    u32 a[4]={v.x,v.y,v.z,v.w};
    #pragma unroll
    for (int q=0;q<4;q++){
      float lo=bf2f((u16)(a[q]&0xFFFFu));
      float hi=bf2f((u16)(a[q]>>16));
      s[q*2]+=lo;   ss[q*2]+=lo*lo;
      s[q*2+1]+=hi; ss[q*2+1]+=hi*hi;
    }
  }
  #pragma unroll
  for (int off=32; off>=8; off>>=1){
    #pragma unroll
    for (int k=0;k<8;k++){
      s[k]+=__shfl_down(s[k],off);
      ss[k]+=__shfl_down(ss[k],off);
    }
  }
  int lane=tid&63, wv=tid>>6;
  if (lane<8){
    #pragma unroll
    for (int k=0;k<8;k++){
      int ch=lane*8+k;
      sred[wv][ch]=s[k];
      sred[wv][64+ch]=ss[k];
    }
  }
  __syncthreads();
  if (tid<128){
    float a=sred[0][tid]+sred[1][tid]+sred[2][tid]+sred[3][tid];
    int ch=tid&63, which=tid>>6;
    atomicAdd(&statsOut[ch*2+which], a);
  }
}

// ---------------------------------------------------------------- layer 1: MFMA rewrite
// 64 rows/block x 8192 blocks, 4 waves. BN0+ReLU fused into staging (bf16, XOR-swizzled
// LDS: byte ^= (row&7)<<4 -- G4 fix for the 128B-row-stride bank conflict). Weights as
// precomputed B-fragments, split bf16 hi+lo (2 MFMAs) => effective f32 weight precision;
// only f32 accumulation ORDER differs from the scalar path (~1e-6).
// Frag maps (m89-verified family): A row=lane&15,k=(lane>>4)*8+e; B col=lane&15 same k;
// C col=lane&15,row=(lane>>4)*4+j.
__global__ __launch_bounds__(256) void k_mm1(u16* __restrict__ Y,
                                             const u16* __restrict__ Wb1h, const u16* __restrict__ Wb1l,
                                             const float* __restrict__ bias1, const float* __restrict__ gf0,
                                             const float* __restrict__ btf0, const float* __restrict__ stats0)
{
  __shared__ u16 Xs[64*64];      // 8KB, swizzled
  __shared__ u16 WH[8*64*8];     // 8KB  [tn*2+k0][lane][e]
  __shared__ u16 WL[8*64*8];     // 8KB
  __shared__ float sc[64], sh[64];
  int tid=threadIdx.x;
  if (tid<64){
    float mu = stats0[tid*2]*INV_ROWS;
    float var= stats0[tid*2+1]*INV_ROWS - mu*mu;
    float rs = 1.0f/sqrtf(var+EPSF);
    float s  = rs*gf0[tid];
    sc[tid]=s; sh[tid]=btf0[tid]-mu*s;
  }
  {
    const uint4* sh4=(const uint4*)Wb1h; uint4* dh4=(uint4*)WH;
    const uint4* sl4=(const uint4*)Wb1l; uint4* dl4=(uint4*)WL;
    dh4[tid]=sh4[tid]; dh4[tid+256]=sh4[tid+256];
    dl4[tid]=sl4[tid]; dl4[tid+256]=sl4[tid+256];
  }
  __syncthreads();
  size_t base=(size_t)blockIdx.x*64;
  // stage: 64 rows x 64 ch, BN0+ReLU, bf16, swizzled
  for (int i=tid;i<512;i+=256){
    int rl=i>>3, c0=(i&7)*8;
    uint4 v=*(const uint4*)(Y + (base+rl)*64 + c0);
    u32 arr[4]={v.x,v.y,v.z,v.w};
    u32 pk[4];
    #pragma unroll
    for (int q=0;q<4;q++){
      int cc=c0+q*2;
      float lo=bf2f((u16)(arr[q]&0xFFFFu));
      float hi=bf2f((u16)(arr[q]>>16));
      lo=fmaxf(0.f, lo*sc[cc]+sh[cc]);
      hi=fmaxf(0.f, hi*sc[cc+1]+sh[cc+1]);
      pk[q] = (u32)f2bf(lo) | ((u32)f2bf(hi)<<16);
    }
    uint4 o4; o4.x=pk[0]; o4.y=pk[1]; o4.z=pk[2]; o4.w=pk[3];
    int byteoff = rl*128 + ((c0*2) ^ ((rl&7)<<4));
    *(uint4*)((char*)Xs + byteoff) = o4;
  }
  __syncthreads();
  int w=tid>>6, lane=tid&63;
  f32x4 acc[4];
  #pragma unroll
  for (int tn=0;tn<4;tn++){ acc[tn][0]=0.f; acc[tn][1]=0.f; acc[tn][2]=0.f; acc[tn][3]=0.f; }
  int arow = w*16 + (lane&15);
  #pragma unroll
  for (int k0=0;k0<2;k0++){
    int aoff = arow*128 + ((k0*64 + (lane>>4)*16) ^ ((arow&7)<<4));
    bf16x8 a = *(const bf16x8*)((const char*)Xs + aoff);
    #pragma unroll
    for (int tn=0;tn<4;tn++){
      bf16x8 bl = *(const bf16x8*)&WL[((tn*2+k0)*64+lane)*8];
      bf16x8 bh = *(const bf16x8*)&WH[((tn*2+k0)*64+lane)*8];
      acc[tn] = __builtin_amdgcn_mfma_f32_16x16x32_bf16(a, bl, acc[tn], 0,0,0);
      acc[tn] = __builtin_amdgcn_mfma_f32_16x16x32_bf16(a, bh, acc[tn], 0,0,0);
    }
  }
  // epilogue: +bias, bf16, in-place store (block-diagonal rows -> in-place safe)
  #pragma unroll
  for (int tn=0;tn<4;tn++){
    int col = tn*16 + (lane&15);
    float bb = bias1[col];
    #pragma unroll
    for (int j=0;j<4;j++){
      int row = w*16 + (lane>>4)*4 + j;
      Y[(base+row)*64 + col] = f2bf(acc[tn][j] + bb);
    }
  }
}

// ---------------------------------------------------------------- layer 2: stats + RAW maxpool (Y2 never stored)
__global__ __launch_bounds__(256) void k_mm2a(const u16* __restrict__ Y1, const float* __restrict__ Wt2,
                                              const float* __restrict__ bias2, const float* __restrict__ gf1,
                                              const float* __restrict__ btf1, const float* __restrict__ stats1,
                                              float* __restrict__ stats2, float* __restrict__ out1)
{
  __shared__ u16 Xs[128*66];
  __shared__ float Wl[64*128];
  __shared__ float sc[64], sh[64];
  __shared__ float res[4][128];
  int tid=threadIdx.x;
  if (tid<64){
    float mu = stats1[tid*2]*INV_ROWS;
    float var= stats1[tid*2+1]*INV_ROWS - mu*mu;
    float rs = 1.0f/sqrtf(var+EPSF);
    float s  = rs*gf1[tid];
    sc[tid]=s; sh[tid]=btf1[tid]-mu*s;
  }
  for (int i=tid;i<64*128;i+=256) Wl[i]=Wt2[i];
  int g=tid>>6, rt=tid&63;
  float bb[32];
  #pragma unroll
  for (int j=0;j<32;j++) bb[j]=bias2[g*32+j];
  float sSum[32], sSq[32];
  #pragma unroll
  for (int j=0;j<32;j++){ sSum[j]=0.f; sSq[j]=0.f; }
  __syncthreads();
  for (int tile=blockIdx.x; tile<4096; tile+=gridDim.x){
    size_t base=(size_t)tile*128;
    for (int i=tid;i<1024;i+=256){
      int rl=i>>3, c0=(i&7)*8;
      uint4 v=*(const uint4*)(Y1 + (base+rl)*64 + c0);
      u32 arr[4]={v.x,v.y,v.z,v.w};
      u16* d=&Xs[rl*66+c0];
      #pragma unroll
      for (int q=0;q<4;q++){
        int cc=c0+q*2;
        float lo=bf2f((u16)(arr[q]&0xFFFFu));
        float hi=bf2f((u16)(arr[q]>>16));
        lo=fmaxf(0.f, lo*sc[cc]+sh[cc]);
        hi=fmaxf(0.f, hi*sc[cc+1]+sh[cc+1]);
        d[q*2]=f2bf(lo); d[q*2+1]=f2bf(hi);
      }
    }
    __syncthreads();
    float acc0[32], acc1[32];
    #pragma unroll
    for (int j=0;j<32;j++){ acc0[j]=0.f; acc1[j]=0.f; }
    const u16* xa=&Xs[rt*66];
    const u16* xb=&Xs[(rt+64)*66];
    for (int c=0;c<64;c++){
      float a=bf2f(xa[c]);
      float bx=bf2f(xb[c]);
      const float4* wr=(const float4*)&Wl[c*128 + g*32];
      #pragma unroll
      for (int o=0;o<8;o++){
        float4 wv=wr[o];
        acc0[o*4+0]+=a*wv.x;  acc0[o*4+1]+=a*wv.y;  acc0[o*4+2]+=a*wv.z;  acc0[o*4+3]+=a*wv.w;
        acc1[o*4+0]+=bx*wv.x; acc1[o*4+1]+=bx*wv.y; acc1[o*4+2]+=bx*wv.z; acc1[o*4+3]+=bx*wv.w;
      }
    }
    #pragma unroll
    for (int j=0;j<32;j++){
      float y0=acc0[j]+bb[j], y1=acc1[j]+bb[j];
      sSum[j]+=y0+y1;
      sSq[j] +=y0*y0+y1*y1;
      float a=y0, b2=y1;
      #pragma unroll
      for (int off=16;off>0;off>>=1){
        a = fmaxf(a, __shfl_down(a, off, 32));
        b2= fmaxf(b2,__shfl_down(b2,off, 32));
      }
      if ((rt&31)==0){
        int o=g*32+j;
        res[rt>>5][o]     = a;
        res[2+(rt>>5)][o] = b2;
      }
    }
    __syncthreads();
    int bm0 = tile*4;
    for (int e=tid;e<512;e+=256){
      int gr=e>>7, o=e&127;
      int bm=bm0+gr; int bi=bm>>11, m=bm&2047;
      out1[((size_t)bi*128+o)*M_ + m] = res[gr][o];
    }
    __syncthreads();
  }
  #pragma unroll
  for (int off=32;off>0;off>>=1){
    #pragma unroll
    for (int j=0;j<32;j++){
      sSum[j]+=__shfl_down(sSum[j],off);
      sSq[j] +=__shfl_down(sSq[j],off);
    }
  }
  if (rt==0){
    #pragma unroll
    for (int j=0;j<32;j++){
      atomicAdd(&stats2[(g*32+j)*2],  sSum[j]);
      atomicAdd(&stats2[(g*32+j)*2+1],sSq[j]);
    }
  }
}

// ---------------------------------------------------------------- final pool: in-place BN2+ReLU on raw maxes
__global__ __launch_bounds__(256) void k_pool(float* __restrict__ out1, const float* __restrict__ stats2,
                                              const float* __restrict__ gf2, const float* __restrict__ btf2)
{
  int idx = blockIdx.x*256 + threadIdx.x;     // 8*128*2048 = 2097152 elements
  int o = (idx >> 11) & 127;
  float mu = stats2[o*2]*INV_ROWS;
  float var= stats2[o*2+1]*INV_ROWS - mu*mu;
  float rs = 1.0f/sqrtf(var+EPSF);
  float s  = rs*gf2[o];
  float sh = btf2[o]-mu*s;
  out1[idx] = fmaxf(0.f, out1[idx]*s + sh);
}

// ---------------------------------------------------------------- launch
extern "C" void kernel_launch(void* const* d_in, const int* in_sizes, int n_in,
                              void* d_out, int out_size, void* d_ws, size_t ws_size,
                              hipStream_t stream)
{
  (void)in_sizes; (void)n_in; (void)out_size; (void)ws_size;
  const float* xyz =(const float*)d_in[0];
  const float* feat=(const float*)d_in[1];
  const float* w0=(const float*)d_in[2],  *b0=(const float*)d_in[3],  *g0=(const float*)d_in[4],  *bt0=(const float*)d_in[5];
  const float* w1=(const float*)d_in[6],  *b1=(const float*)d_in[7],  *g1=(const float*)d_in[8],  *bt1=(const float*)d_in[9];
  const float* w2=(const float*)d_in[10], *b2=(const float*)d_in[11], *g2=(const float*)d_in[12], *bt2=(const float*)d_in[13];
  float* out0=(float*)d_out;
  float* out1=out0 + (size_t)B_*M_*3;

  char* ws=(char*)d_ws;
  float* nxyz =(float*)(ws);              // 196608 B used
  u16*   Wb1h =(u16*)  (ws + 196608);     // 8192 B  (slack inside nxyz region)
  u16*   Wb1l =(u16*)  (ws + 204800);     // 8192 B  (ends 212992 < 262144)
  int*   knn  =(int*)  (ws + 262144);     // 2097152
  float* Wt0  =(float*)(ws + 2359296);    // 17408
  float* Wt1  =(float*)(ws + 2376704);    // 16384
  float* Wt2  =(float*)(ws + 2393088);    // 32768
  float* biasf=(float*)(ws + 2425856);    // 1536
  float* gfp  =(float*)(ws + 2427392);    // 1536
  float* btfp =(float*)(ws + 2428928);    // 1536
  float* stats=(float*)(ws + 2430464);    // 3072
  u16*   featT=(u16*)  (ws + 2433536);    // 8388608
  u16*   Y0   =(u16*)  (ws + 10822144);   // 67108864  (total ~78 MB)

  k_prep<<<1,256,0,stream>>>(w0,b0,g0,bt0,w1,b1,g1,bt1,w2,b2,g2,bt2,Wt0,Wt1,Wt2,biasf,gfp,btfp,stats,Wb1h,Wb1l);
  k_tr<<<dim3(128,8),256,0,stream>>>(feat, featT);
  k_fps<<<B_,512,0,stream>>>(xyz, nxyz, out0);
  k_bq<<<2048,512,0,stream>>>(xyz, nxyz, knn);
  k_mm0<<<2048,256,0,stream>>>(xyz, featT, knn, nxyz, Wt0, biasf+0, Y0);
  k_stats<64><<<128,256,0,stream>>>(Y0, stats+0);
  k_mm1<<<8192,256,0,stream>>>(Y0, Wb1h, Wb1l, biasf+128, gfp+0, btfp+0, stats+0);
  k_stats<64><<<128,256,0,stream>>>(Y0, stats+256);
  k_mm2a<<<512,256,0,stream>>>(Y0, Wt2, biasf+256, gfp+128, btfp+128, stats+256, stats+512, out1);
  k_pool<<<8192,256,0,stream>>>(out1, stats+512, gfp+256, btfp+256);
}

// Round 6
// 2360.446 us; speedup vs baseline: 1.4000x; 1.1302x over previous
//
#include <hip/hip_runtime.h>
#include <hip/hip_bf16.h>
#include <stdint.h>

typedef unsigned short u16;
typedef unsigned int   u32;
typedef unsigned long long u64;
typedef float v2f __attribute__((ext_vector_type(2)));
typedef __attribute__((ext_vector_type(8))) short bf16x8;
typedef __attribute__((ext_vector_type(4))) float f32x4;

#define B_    8
#define N_    8192
#define M_    2048
#define NS_   32
#define CIN_  64
#define ROWS_ (B_*M_*NS_)          // 524288
#define BIGF  1e10f
#define EPSF  1e-5f
#define INV_ROWS (1.0f/524288.0f)  // 2^-19, exact

__device__ __forceinline__ u16 f2bf(float f){
  u32 x=__float_as_uint(f);
  return (u16)((x + 0x7FFFu + ((x>>16)&1u))>>16);   // RNE
}
__device__ __forceinline__ float bf2f(u16 u){ return __uint_as_float(((u32)u)<<16); }

// DPP full-wave max of non-negative u64 keys; result lands in lane 63.
__device__ __forceinline__ u64 wave_max_key(u64 k){
#define DPP_LVL(CTRL) { \
    u32 lo_=(u32)__builtin_amdgcn_update_dpp(0,(int)(u32)k,(CTRL),0xF,0xF,true); \
    u32 hi_=(u32)__builtin_amdgcn_update_dpp(0,(int)(u32)(k>>32),(CTRL),0xF,0xF,true); \
    u64 o_=((u64)hi_<<32)|(u64)lo_; \
    k=(o_>k)?o_:k; }
  DPP_LVL(0x111)  // row_shr:1
  DPP_LVL(0x112)  // row_shr:2
  DPP_LVL(0x114)  // row_shr:4
  DPP_LVL(0x118)  // row_shr:8
  DPP_LVL(0x142)  // row_bcast:15
  DPP_LVL(0x143)  // row_bcast:31  -> lane 63 holds wave max
#undef DPP_LVL
  return k;
}

// ---------------------------------------------------------------- prep (fp32 weights in)
// B-frag layout (16x16x32): col = tn*16 + (lane&15), k = k0*32 + ((lane>>4)&3)*8 + e.
// Split precision: w = bf16(hi) + bf16(w - hi)  (~2^-17 rel error).
__global__ __launch_bounds__(256) void k_prep(
    const float* w0,const float* b0,const float* g0,const float* bt0,
    const float* w1,const float* b1,const float* g1,const float* bt1,
    const float* w2,const float* b2,const float* g2,const float* bt2,
    float* Wt0,float* Wt1,float* Wt2,
    float* biasf,float* gf,float* btf,float* stats,
    u16* Wb1h, u16* Wb1l, u16* Wb2h, u16* Wb2l)
{
  int tid=threadIdx.x;
  for (int i=tid;i<768;i+=256) stats[i]=0.f;
  for (int i=tid;i<67*64;i+=256){ int c=i>>6,o=i&63;  Wt0[c*64+o]=w0[o*67+c]; }
  for (int i=tid;i<64*64;i+=256){ int c=i>>6,o=i&63;  Wt1[c*64+o]=w1[o*64+c]; }
  for (int i=tid;i<64*128;i+=256){int c=i>>7,o=i&127; Wt2[c*128+o]=w2[o*64+c]; }
  // W1 B-fragments (64 cols -> tn 0..3)
  for (int i=tid;i<4096;i+=256){
    int e=i&7, lane=(i>>3)&63, k0=(i>>9)&1, tn=i>>10;
    int col = tn*16 + (lane&15);
    int k   = k0*32 + ((lane>>4)&3)*8 + e;
    float v = w1[col*64 + k];
    u16 hib = f2bf(v);
    Wb1h[i] = hib;
    Wb1l[i] = f2bf(v - bf2f(hib));
  }
  // W2 B-fragments (128 cols -> tn 0..7)
  for (int i=tid;i<8192;i+=256){
    int e=i&7, lane=(i>>3)&63, k0=(i>>9)&1, tn=i>>10;
    int col = tn*16 + (lane&15);
    int k   = k0*32 + ((lane>>4)&3)*8 + e;
    float v = w2[col*64 + k];
    u16 hib = f2bf(v);
    Wb2h[i] = hib;
    Wb2l[i] = f2bf(v - bf2f(hib));
  }
  if (tid<64){
    biasf[0*128+tid]=b0[tid]; gf[0*128+tid]=g0[tid]; btf[0*128+tid]=bt0[tid];
    biasf[1*128+tid]=b1[tid]; gf[1*128+tid]=g1[tid]; btf[1*128+tid]=bt1[tid];
  }
  if (tid<128){
    biasf[2*128+tid]=b2[tid]; gf[2*128+tid]=g2[tid]; btf[2*128+tid]=bt2[tid];
  }
}

// ------------------------------------------------------- feature transpose
__global__ __launch_bounds__(256) void k_tr(const float* __restrict__ feats, u16* __restrict__ featT)
{
  __shared__ float t[64][65];
  int bb=blockIdx.y, n0=blockIdx.x*64, tid=threadIdx.x;
  int a=tid&63, q=tid>>6;
  const float* fp = feats + (size_t)bb*CIN_*N_;
  #pragma unroll
  for (int s=0;s<16;s++){ int c=q*16+s; t[c][a]=fp[(size_t)c*N_ + n0 + a]; }
  __syncthreads();
  u16* op = featT + (size_t)bb*N_*CIN_;
  #pragma unroll
  for (int s=0;s<16;s++){ int n=q*16+s; op[(size_t)(n0+n)*CIN_ + a] = f2bf(t[a][n]); }
}

// ---------------------------------------------------------------- FPS (R1 measured-best, frozen)
__global__ __launch_bounds__(512) void k_fps(const float* __restrict__ xyz,
                                             float* __restrict__ nxyz, float* __restrict__ out0)
{
#pragma clang fp contract(off)
  __shared__ float sx[N_], sy[N_], sz[N_];
  __shared__ int sidx[M_];
  __shared__ u64 skey[2][8];
  int b=blockIdx.x, tid=threadIdx.x;
  const float* xp = xyz + (size_t)b*N_*3;
  for (int i=tid;i<N_;i+=512){ sx[i]=xp[i*3]; sy[i]=xp[i*3+1]; sz[i]=xp[i*3+2]; }
  __syncthreads();
  v2f px[8],py[8],pz[8],md[8];
  int base = tid*16;
  #pragma unroll
  for (int p=0;p<8;p++){
    px[p]=*(const v2f*)&sx[base+2*p];
    py[p]=*(const v2f*)&sy[base+2*p];
    pz[p]=*(const v2f*)&sz[base+2*p];
    v2f m0; m0[0]=BIGF; m0[1]=BIGF; md[p]=m0;
  }
  u32 invb = 0xFFFFFFFFu - (u32)base;
  int far=0;
  int lane=tid&63, wv=tid>>6;
  for (int step=0; step<M_; step++){
    if (tid==0) sidx[step]=far;          // PRE-update emission
    float cxs=sx[far], cys=sy[far], czs=sz[far];
    v2f cx; cx[0]=cxs; cx[1]=cxs;
    v2f cy; cy[0]=cys; cy[1]=cys;
    v2f cz; cz[0]=czs; cz[1]=czs;
    u64 kb=0;
    #pragma unroll
    for (int p=0;p<8;p++){
      v2f dx=px[p]-cx, dy=py[p]-cy, dz=pz[p]-cz;
      v2f d=(dx*dx+dy*dy)+dz*dz;         // contract off: same assoc as ((xx+yy)+zz)
      v2f m=__builtin_elementwise_min(md[p],d);
      md[p]=m;
      u64 k0=((u64)__float_as_uint(m[0])<<32)|(u64)(invb-(u32)(2*p));
      u64 k1=((u64)__float_as_uint(m[1])<<32)|(u64)(invb-(u32)(2*p+1));
      u64 kp=(k1>k0)?k1:k0;              // equal dist -> k0 (lower idx) wins: larger ~idx
      kb=(kp>kb)?kp:kb;
    }
    kb = wave_max_key(kb);
    int par = step & 1;
    if (lane==63) skey[par][wv]=kb;
    __syncthreads();                     // single barrier per step
    u64 a0=skey[par][0],a1=skey[par][1],a2=skey[par][2],a3=skey[par][3];
    u64 a4=skey[par][4],a5=skey[par][5],a6=skey[par][6],a7=skey[par][7];
    a0=(a1>a0)?a1:a0; a2=(a3>a2)?a3:a2; a4=(a5>a4)?a5:a4; a6=(a7>a6)?a7:a6;
    a0=(a2>a0)?a2:a0; a4=(a6>a4)?a6:a4;
    a0=(a4>a0)?a4:a0;
    far = (int)(0xFFFFFFFFu - (u32)(a0 & 0xFFFFFFFFull));
  }
  for (int i=tid;i<M_;i+=512){
    int id = sidx[i];
    float x=sx[id], y=sy[id], z=sz[id];
    size_t o=(size_t)(b*M_+i)*3;
    nxyz[o]=x; nxyz[o+1]=y; nxyz[o+2]=z;
    out0[o]=x; out0[o+1]=y; out0[o+2]=z;
  }
}

// ---------------------------------------------------------------- ball query
#define BQCAP 512
__global__ __launch_bounds__(512) void k_bq(const float* __restrict__ xyz, const float* __restrict__ nxyz,
                                            int* __restrict__ knn)
{
  __shared__ float4 sP[N_];
  __shared__ float candd[8][BQCAP];
  __shared__ u16  candi[8][BQCAP];
  int tid=threadIdx.x;
  int cid0 = blockIdx.x*8;
  int b = cid0 >> 11;
  const float* xp = xyz + (size_t)b*N_*3;
  for (int i=tid;i<N_;i+=512){
    float x=xp[i*3], y=xp[i*3+1], z=xp[i*3+2];
    float x2 = __fmul_rn(x,x);
    x2 = __fadd_rn(x2, __fmul_rn(y,y));
    x2 = __fadd_rn(x2, __fmul_rn(z,z));
    sP[i]=make_float4(x,y,z,x2);
  }
  __syncthreads();
  int w=tid>>6, lane=tid&63;
  int cid = cid0 + w;
  float cx=nxyz[(size_t)cid*3], cy=nxyz[(size_t)cid*3+1], cz=nxyz[(size_t)cid*3+2];
  float c2 = __fmul_rn(cx,cx);
  c2 = __fadd_rn(c2, __fmul_rn(cy,cy));
  c2 = __fadd_rn(c2, __fmul_rn(cz,cz));
  int cnt=0;
  for (int i0=0;i0<N_;i0+=64){
    int i=i0+lane;
    float4 p=sP[i];
    float dot = __fmul_rn(cx,p.x);
    dot = __fadd_rn(dot, __fmul_rn(cy,p.y));
    dot = __fadd_rn(dot, __fmul_rn(cz,p.z));
    float d2 = __fsub_rn(__fadd_rn(c2,p.w), __fmul_rn(2.0f,dot));
    float d = sqrtf(fmaxf(d2,0.f));
    bool in = (d <= 0.4f);
    u64 msk = __ballot(in);
    int pos = cnt + __popcll(msk & ((1ull<<lane)-1ull));
    if (in && pos<BQCAP){ candd[w][pos]=d; candi[w][pos]=(u16)i; }
    cnt += __popcll(msk);
  }
  int R = cnt<BQCAP ? cnt : BQCAP;
  int* kout = knn + (size_t)cid*NS_;
  if (R >= NS_){
    for (int s=0;s<NS_;s++){
      u64 kb = ~0ull;                    // min identity
      for (int j=lane;j<R;j+=64){
        float v=candd[w][j];
        u64 k = ((u64)__float_as_uint(v)<<32) | (u64)(u32)j;
        kb = (k<kb)?k:kb;
      }
      u64 inv = wave_max_key(~kb);       // min via complemented max
      if (lane==63){
        u64 kw = ~inv;
        int bpp = (int)(u32)(kw & 0xFFFFFFFFull);
        kout[s]=candi[w][bpp];
        candd[w][bpp]=3e38f;             // same-wave DS in-order: visible next pass
      }
    }
  } else {
    if (lane<R) kout[lane]=candi[w][lane];
    int need = NS_-R, slot = R;
    for (int i0=0; i0<N_ && need>0; i0+=64){
      int i=i0+lane;
      float4 p=sP[i];
      float dot = __fmul_rn(cx,p.x);
      dot = __fadd_rn(dot, __fmul_rn(cy,p.y));
      dot = __fadd_rn(dot, __fmul_rn(cz,p.z));
      float d2 = __fsub_rn(__fadd_rn(c2,p.w), __fmul_rn(2.0f,dot));
      float d = sqrtf(fmaxf(d2,0.f));
      bool in = (d <= 0.4f);
      u64 mm = __ballot(!in);
      while (mm && need>0){
        int bpos = __ffsll((long long)mm)-1;
        if (lane==0) kout[slot] = i0+bpos;
        slot++; need--;
        mm &= mm-1;
      }
    }
  }
}

// ---------------------------------------------------------------- layer 0 (gather+concat fused)
__global__ __launch_bounds__(256) void k_mm0(const float* __restrict__ xyz, const u16* __restrict__ featT,
                                             const int* __restrict__ knn, const float* __restrict__ nxyz,
                                             const float* __restrict__ Wt0, const float* __restrict__ biasf,
                                             u16* __restrict__ Y0)
{
  __shared__ u16 Xs[256*70];
  __shared__ float Wl[67*64];
  int tid=threadIdx.x;
  for (int i=tid;i<67*64;i+=256) Wl[i]=Wt0[i];
  int base = blockIdx.x*256;
  {
    int row = base + tid;
    int bm  = row >> 5;
    int b   = row >> 16;
    int n   = knn[row];
    const float* cp = nxyz + (size_t)bm*3;
    const float* xp = xyz + ((size_t)b*N_ + n)*3;
    u16* xr = &Xs[tid*70];
    xr[0]=f2bf(xp[0]-cp[0]);
    xr[1]=f2bf(xp[1]-cp[1]);
    xr[2]=f2bf(xp[2]-cp[2]);
    const uint4* fp = (const uint4*)(featT + ((size_t)b*N_ + n)*CIN_);
    #pragma unroll
    for (int i=0;i<8;i++){
      uint4 v=fp[i];
      u16* d = xr + 3 + i*8;
      d[0]=(u16)(v.x&0xFFFFu); d[1]=(u16)(v.x>>16);
      d[2]=(u16)(v.y&0xFFFFu); d[3]=(u16)(v.y>>16);
      d[4]=(u16)(v.z&0xFFFFu); d[5]=(u16)(v.z>>16);
      d[6]=(u16)(v.w&0xFFFFu); d[7]=(u16)(v.w>>16);
    }
  }
  __syncthreads();
  int g=tid>>7, rt=tid&127;
  float acc0[32], acc1[32];
  #pragma unroll
  for (int j=0;j<32;j++){ acc0[j]=0.f; acc1[j]=0.f; }
  const u16* xa=&Xs[rt*70];
  const u16* xb=&Xs[(rt+128)*70];
  for (int c=0;c<67;c++){
    float a=bf2f(xa[c]);
    float bx=bf2f(xb[c]);
    const float4* wr=(const float4*)&Wl[c*64 + g*32];
    #pragma unroll
    for (int o=0;o<8;o++){
      float4 wv=wr[o];
      acc0[o*4+0]+=a*wv.x;  acc0[o*4+1]+=a*wv.y;  acc0[o*4+2]+=a*wv.z;  acc0[o*4+3]+=a*wv.w;
      acc1[o*4+0]+=bx*wv.x; acc1[o*4+1]+=bx*wv.y; acc1[o*4+2]+=bx*wv.z; acc1[o*4+3]+=bx*wv.w;
    }
  }
  float bb[32];
  #pragma unroll
  for (int j=0;j<32;j++) bb[j]=biasf[g*32+j];
  u16* y0p = Y0 + ((size_t)(base+rt))*64 + g*32;
  u16* y1p = Y0 + ((size_t)(base+rt+128))*64 + g*32;
  #pragma unroll
  for (int j=0;j<32;j++){
    y0p[j]=f2bf(acc0[j]+bb[j]);
    y1p[j]=f2bf(acc1[j]+bb[j]);
  }
}

// ---------------------------------------------------------------- channel stats (sum, sumsq)
template<int C>
__global__ __launch_bounds__(256) void k_stats(const u16* __restrict__ Y, float* __restrict__ statsOut)
{
  __shared__ float sred[4][128];
  int tid=threadIdx.x;
  int c0=(tid&7)*8;          // 8 channels per thread
  int rg=tid>>3;             // 32 row-groups per block
  float s[8], ss[8];
  #pragma unroll
  for (int k=0;k<8;k++){ s[k]=0.f; ss[k]=0.f; }
  for (size_t r=(size_t)blockIdx.x*32+rg; r<ROWS_; r+=(size_t)gridDim.x*32){
    uint4 v=*(const uint4*)&Y[r*64+c0];
    u32 a[4]={v.x,v.y,v.z,v.w};
    #pragma unroll
    for (int q=0;q<4;q++){
      float lo=bf2f((u16)(a[q]&0xFFFFu));
      float hi=bf2f((u16)(a[q]>>16));
      s[q*2]+=lo;   ss[q*2]+=lo*lo;
      s[q*2+1]+=hi; ss[q*2+1]+=hi*hi;
    }
  }
  #pragma unroll
  for (int off=32; off>=8; off>>=1){
    #pragma unroll
    for (int k=0;k<8;k++){
      s[k]+=__shfl_down(s[k],off);
      ss[k]+=__shfl_down(ss[k],off);
    }
  }
  int lane=tid&63, wv=tid>>6;
  if (lane<8){
    #pragma unroll
    for (int k=0;k<8;k++){
      int ch=lane*8+k;
      sred[wv][ch]=s[k];
      sred[wv][64+ch]=ss[k];
    }
  }
  __syncthreads();
  if (tid<128){
    float a=sred[0][tid]+sred[1][tid]+sred[2][tid]+sred[3][tid];
    int ch=tid&63, which=tid>>6;
    atomicAdd(&statsOut[ch*2+which], a);
  }
}

// ---------------------------------------------------------------- layer 1: MFMA (proven R5)
__global__ __launch_bounds__(256) void k_mm1(u16* __restrict__ Y,
                                             const u16* __restrict__ Wb1h, const u16* __restrict__ Wb1l,
                                             const float* __restrict__ bias1, const float* __restrict__ gf0,
                                             const float* __restrict__ btf0, const float* __restrict__ stats0)
{
  __shared__ u16 Xs[64*64];      // 8KB, swizzled
  __shared__ u16 WH[8*64*8];     // 8KB  [tn*2+k0][lane][e]
  __shared__ u16 WL[8*64*8];     // 8KB
  __shared__ float sc[64], sh[64];
  int tid=threadIdx.x;
  if (tid<64){
    float mu = stats0[tid*2]*INV_ROWS;
    float var= stats0[tid*2+1]*INV_ROWS - mu*mu;
    float rs = 1.0f/sqrtf(var+EPSF);
    float s  = rs*gf0[tid];
    sc[tid]=s; sh[tid]=btf0[tid]-mu*s;
  }
  {
    const uint4* sh4=(const uint4*)Wb1h; uint4* dh4=(uint4*)WH;
    const uint4* sl4=(const uint4*)Wb1l; uint4* dl4=(uint4*)WL;
    dh4[tid]=sh4[tid]; dh4[tid+256]=sh4[tid+256];
    dl4[tid]=sl4[tid]; dl4[tid+256]=sl4[tid+256];
  }
  __syncthreads();
  size_t base=(size_t)blockIdx.x*64;
  for (int i=tid;i<512;i+=256){
    int rl=i>>3, c0=(i&7)*8;
    uint4 v=*(const uint4*)(Y + (base+rl)*64 + c0);
    u32 arr[4]={v.x,v.y,v.z,v.w};
    u32 pk[4];
    #pragma unroll
    for (int q=0;q<4;q++){
      int cc=c0+q*2;
      float lo=bf2f((u16)(arr[q]&0xFFFFu));
      float hi=bf2f((u16)(arr[q]>>16));
      lo=fmaxf(0.f, lo*sc[cc]+sh[cc]);
      hi=fmaxf(0.f, hi*sc[cc+1]+sh[cc+1]);
      pk[q] = (u32)f2bf(lo) | ((u32)f2bf(hi)<<16);
    }
    uint4 o4; o4.x=pk[0]; o4.y=pk[1]; o4.z=pk[2]; o4.w=pk[3];
    int byteoff = rl*128 + ((c0*2) ^ ((rl&7)<<4));
    *(uint4*)((char*)Xs + byteoff) = o4;
  }
  __syncthreads();
  int w=tid>>6, lane=tid&63;
  f32x4 acc[4];
  #pragma unroll
  for (int tn=0;tn<4;tn++){ acc[tn][0]=0.f; acc[tn][1]=0.f; acc[tn][2]=0.f; acc[tn][3]=0.f; }
  int arow = w*16 + (lane&15);
  #pragma unroll
  for (int k0=0;k0<2;k0++){
    int aoff = arow*128 + ((k0*64 + (lane>>4)*16) ^ ((arow&7)<<4));
    bf16x8 a = *(const bf16x8*)((const char*)Xs + aoff);
    #pragma unroll
    for (int tn=0;tn<4;tn++){
      bf16x8 bl = *(const bf16x8*)&WL[((tn*2+k0)*64+lane)*8];
      bf16x8 bh = *(const bf16x8*)&WH[((tn*2+k0)*64+lane)*8];
      acc[tn] = __builtin_amdgcn_mfma_f32_16x16x32_bf16(a, bl, acc[tn], 0,0,0);
      acc[tn] = __builtin_amdgcn_mfma_f32_16x16x32_bf16(a, bh, acc[tn], 0,0,0);
    }
  }
  #pragma unroll
  for (int tn=0;tn<4;tn++){
    int col = tn*16 + (lane&15);
    float bb = bias1[col];
    #pragma unroll
    for (int j=0;j<4;j++){
      int row = w*16 + (lane>>4)*4 + j;
      Y[(base+row)*64 + col] = f2bf(acc[tn][j] + bb);
    }
  }
}

// ---------------------------------------------------------------- layer 2: MFMA + stats + RAW maxpool
// Same template as k_mm1. 8192 tiles x 64 rows (2 centroid groups of 32), grid-stride.
// Raw y (pre-BN2) -> swizzled f32 LDS Ys[64][128] -> per-(group,channel) maxpool to out1
// + per-channel sum/sumsq accumulated in registers, block-reduced to 512/addr atomics.
// BN2+ReLU applied later by k_pool (monotone per channel: unchanged argument).
__global__ __launch_bounds__(256) void k_mm2a(const u16* __restrict__ Y1,
                                              const u16* __restrict__ Wb2h, const u16* __restrict__ Wb2l,
                                              const float* __restrict__ bias2, const float* __restrict__ gf1,
                                              const float* __restrict__ btf1, const float* __restrict__ stats1,
                                              float* __restrict__ stats2, float* __restrict__ out1)
{
  __shared__ u16 Xs[64*64];       // 8KB swizzled bf16 (row stride 128B)
  __shared__ u16 WH[8192];        // 16KB [tn*2+k0][lane][e], tn 0..7
  __shared__ u16 WL[8192];        // 16KB
  __shared__ float Ys[64*128];    // 32KB raw y, swizzled (row stride 512B)
  __shared__ float sc[64], sh[64];
  __shared__ float sred[512];
  int tid=threadIdx.x;
  if (tid<64){
    float mu = stats1[tid*2]*INV_ROWS;
    float var= stats1[tid*2+1]*INV_ROWS - mu*mu;
    float rs = 1.0f/sqrtf(var+EPSF);
    float s  = rs*gf1[tid];
    sc[tid]=s; sh[tid]=btf1[tid]-mu*s;
  }
  {
    const uint4* s4=(const uint4*)Wb2h; uint4* d4=(uint4*)WH;
    const uint4* s5=(const uint4*)Wb2l; uint4* d5=(uint4*)WL;
    for (int i=tid;i<1024;i+=256){ d4[i]=s4[i]; d5[i]=s5[i]; }
  }
  int w=tid>>6, lane=tid&63;
  int pg=tid>>7, po=tid&127;      // pool assignment: group (0,1), channel
  float bias_po_unused; (void)bias_po_unused;
  float accSum=0.f, accSq=0.f;    // per-thread channel stats across tiles
  __syncthreads();
  for (int tile=blockIdx.x; tile<8192; tile+=gridDim.x){
    size_t base=(size_t)tile*64;
    // stage 64x64: BN1+ReLU, bf16, swizzled (mm1 pattern)
    for (int i=tid;i<512;i+=256){
      int rl=i>>3, c0=(i&7)*8;
      uint4 v=*(const uint4*)(Y1 + (base+rl)*64 + c0);
      u32 arr[4]={v.x,v.y,v.z,v.w};
      u32 pk[4];
      #pragma unroll
      for (int q=0;q<4;q++){
        int cc=c0+q*2;
        float lo=bf2f((u16)(arr[q]&0xFFFFu));
        float hi=bf2f((u16)(arr[q]>>16));
        lo=fmaxf(0.f, lo*sc[cc]+sh[cc]);
        hi=fmaxf(0.f, hi*sc[cc+1]+sh[cc+1]);
        pk[q] = (u32)f2bf(lo) | ((u32)f2bf(hi)<<16);
      }
      uint4 o4; o4.x=pk[0]; o4.y=pk[1]; o4.z=pk[2]; o4.w=pk[3];
      int byteoff = rl*128 + ((c0*2) ^ ((rl&7)<<4));
      *(uint4*)((char*)Xs + byteoff) = o4;
    }
    __syncthreads();
    // MFMA: wave w -> rows w*16..w*16+15, 8 col-tiles, K=64, hi+lo
    f32x4 acc[8];
    #pragma unroll
    for (int tn=0;tn<8;tn++){ acc[tn][0]=0.f; acc[tn][1]=0.f; acc[tn][2]=0.f; acc[tn][3]=0.f; }
    int arow = w*16 + (lane&15);
    #pragma unroll
    for (int k0=0;k0<2;k0++){
      int aoff = arow*128 + ((k0*64 + (lane>>4)*16) ^ ((arow&7)<<4));
      bf16x8 a = *(const bf16x8*)((const char*)Xs + aoff);
      #pragma unroll
      for (int tn=0;tn<8;tn++){
        bf16x8 bl = *(const bf16x8*)&WL[((tn*2+k0)*64+lane)*8];
        bf16x8 bh = *(const bf16x8*)&WH[((tn*2+k0)*64+lane)*8];
        acc[tn] = __builtin_amdgcn_mfma_f32_16x16x32_bf16(a, bl, acc[tn], 0,0,0);
        acc[tn] = __builtin_amdgcn_mfma_f32_16x16x32_bf16(a, bh, acc[tn], 0,0,0);
      }
    }
    // write raw y = acc + bias to swizzled Ys
    #pragma unroll
    for (int tn=0;tn<8;tn++){
      int col = tn*16 + (lane&15);
      float bb = bias2[col];
      #pragma unroll
      for (int j=0;j<4;j++){
        int row = w*16 + (lane>>4)*4 + j;
        int byteoff = row*512 + ((col*4) ^ ((row&7)<<4));
        *(float*)((char*)Ys + byteoff) = acc[tn][j] + bb;
      }
    }
    __syncthreads();
    // pool over 32 rows + channel stats
    {
      float mx=-3e38f;
      #pragma unroll 4
      for (int k=0;k<32;k++){
        int row = pg*32 + k;
        int byteoff = row*512 + ((po*4) ^ ((row&7)<<4));
        float y = *(const float*)((const char*)Ys + byteoff);
        accSum += y; accSq += y*y;
        mx = fmaxf(mx, y);
      }
      int bm = tile*2 + pg; int bi = bm>>11, m = bm&2047;
      out1[((size_t)bi*128+po)*M_ + m] = mx;
    }
    __syncthreads();   // protect Xs/Ys for next tile
  }
  // block reduce stats -> atomics (grid 512 -> 512 adds/address, same as prior version)
  sred[tid]      = accSum;
  sred[256+tid]  = accSq;
  __syncthreads();
  if (tid<128){
    float s = sred[tid] + sred[tid+128];
    float q = sred[256+tid] + sred[256+tid+128];
    atomicAdd(&stats2[tid*2],   s);
    atomicAdd(&stats2[tid*2+1], q);
  }
}

// ---------------------------------------------------------------- final pool: in-place BN2+ReLU on raw maxes
__global__ __launch_bounds__(256) void k_pool(float* __restrict__ out1, const float* __restrict__ stats2,
                                              const float* __restrict__ gf2, const float* __restrict__ btf2)
{
  int idx = blockIdx.x*256 + threadIdx.x;     // 8*128*2048 = 2097152 elements
  int o = (idx >> 11) & 127;
  float mu = stats2[o*2]*INV_ROWS;
  float var= stats2[o*2+1]*INV_ROWS - mu*mu;
  float rs = 1.0f/sqrtf(var+EPSF);
  float s  = rs*gf2[o];
  float sh = btf2[o]-mu*s;
  out1[idx] = fmaxf(0.f, out1[idx]*s + sh);
}

// ---------------------------------------------------------------- launch
extern "C" void kernel_launch(void* const* d_in, const int* in_sizes, int n_in,
                              void* d_out, int out_size, void* d_ws, size_t ws_size,
                              hipStream_t stream)
{
  (void)in_sizes; (void)n_in; (void)out_size; (void)ws_size;
  const float* xyz =(const float*)d_in[0];
  const float* feat=(const float*)d_in[1];
  const float* w0=(const float*)d_in[2],  *b0=(const float*)d_in[3],  *g0=(const float*)d_in[4],  *bt0=(const float*)d_in[5];
  const float* w1=(const float*)d_in[6],  *b1=(const float*)d_in[7],  *g1=(const float*)d_in[8],  *bt1=(const float*)d_in[9];
  const float* w2=(const float*)d_in[10], *b2=(const float*)d_in[11], *g2=(const float*)d_in[12], *bt2=(const float*)d_in[13];
  float* out0=(float*)d_out;
  float* out1=out0 + (size_t)B_*M_*3;

  char* ws=(char*)d_ws;
  float* nxyz =(float*)(ws);              // 196608 B used
  u16*   Wb1h =(u16*)  (ws + 196608);     // 8192 B
  u16*   Wb1l =(u16*)  (ws + 204800);     // 8192 B
  u16*   Wb2h =(u16*)  (ws + 212992);     // 16384 B
  u16*   Wb2l =(u16*)  (ws + 229376);     // 16384 B (ends 245760 < 262144)
  int*   knn  =(int*)  (ws + 262144);     // 2097152
  float* Wt0  =(float*)(ws + 2359296);    // 17408
  float* Wt1  =(float*)(ws + 2376704);    // 16384
  float* Wt2  =(float*)(ws + 2393088);    // 32768
  float* biasf=(float*)(ws + 2425856);    // 1536
  float* gfp  =(float*)(ws + 2427392);    // 1536
  float* btfp =(float*)(ws + 2428928);    // 1536
  float* stats=(float*)(ws + 2430464);    // 3072
  u16*   featT=(u16*)  (ws + 2433536);    // 8388608
  u16*   Y0   =(u16*)  (ws + 10822144);   // 67108864  (total ~78 MB)

  k_prep<<<1,256,0,stream>>>(w0,b0,g0,bt0,w1,b1,g1,bt1,w2,b2,g2,bt2,Wt0,Wt1,Wt2,biasf,gfp,btfp,stats,
                             Wb1h,Wb1l,Wb2h,Wb2l);
  k_tr<<<dim3(128,8),256,0,stream>>>(feat, featT);
  k_fps<<<B_,512,0,stream>>>(xyz, nxyz, out0);
  k_bq<<<2048,512,0,stream>>>(xyz, nxyz, knn);
  k_mm0<<<2048,256,0,stream>>>(xyz, featT, knn, nxyz, Wt0, biasf+0, Y0);
  k_stats<64><<<128,256,0,stream>>>(Y0, stats+0);
  k_mm1<<<8192,256,0,stream>>>(Y0, Wb1h, Wb1l, biasf+128, gfp+0, btfp+0, stats+0);
  k_stats<64><<<128,256,0,stream>>>(Y0, stats+256);
  k_mm2a<<<512,256,0,stream>>>(Y0, Wb2h, Wb2l, biasf+256, gfp+128, btfp+128, stats+256, stats+512, out1);
  k_pool<<<8192,256,0,stream>>>(out1, stats+512, gfp+256, btfp+256);
}

// Round 7
// 2315.714 us; speedup vs baseline: 1.4270x; 1.0193x over previous
//
#include <hip/hip_runtime.h>
#include <hip/hip_bf16.h>
#include <stdint.h>

typedef unsigned short u16;
typedef unsigned int   u32;
typedef unsigned long long u64;
typedef float v2f __attribute__((ext_vector_type(2)));
typedef __attribute__((ext_vector_type(8))) short bf16x8;
typedef __attribute__((ext_vector_type(4))) float f32x4;

#define B_    8
#define N_    8192
#define M_    2048
#define NS_   32
#define CIN_  64
#define ROWS_ (B_*M_*NS_)          // 524288
#define BIGF  1e10f
#define EPSF  1e-5f
#define INV_ROWS (1.0f/524288.0f)  // 2^-19, exact

__device__ __forceinline__ u16 f2bf(float f){
  u32 x=__float_as_uint(f);
  return (u16)((x + 0x7FFFu + ((x>>16)&1u))>>16);   // RNE
}
__device__ __forceinline__ float bf2f(u16 u){ return __uint_as_float(((u32)u)<<16); }

// DPP full-wave max of non-negative u64 keys; result lands in lane 63.
__device__ __forceinline__ u64 wave_max_key(u64 k){
#define DPP_LVL(CTRL) { \
    u32 lo_=(u32)__builtin_amdgcn_update_dpp(0,(int)(u32)k,(CTRL),0xF,0xF,true); \
    u32 hi_=(u32)__builtin_amdgcn_update_dpp(0,(int)(u32)(k>>32),(CTRL),0xF,0xF,true); \
    u64 o_=((u64)hi_<<32)|(u64)lo_; \
    k=(o_>k)?o_:k; }
  DPP_LVL(0x111)  // row_shr:1
  DPP_LVL(0x112)  // row_shr:2
  DPP_LVL(0x114)  // row_shr:4
  DPP_LVL(0x118)  // row_shr:8
  DPP_LVL(0x142)  // row_bcast:15
  DPP_LVL(0x143)  // row_bcast:31  -> lane 63 holds wave max
#undef DPP_LVL
  return k;
}

// ---------------------------------------------------------------- prep (fp32 weights in)
// B-frag layout (16x16x32): col = tn*16 + (lane&15), k = k0*32 + ((lane>>4)&3)*8 + e.
// Split precision: w = bf16(hi) + bf16(w - hi)  (~2^-17 rel error).
// W0 fragments use the STAGED channel order: k<64 -> feat ch (w0 col 3+k),
// 64<=k<67 -> xyz ch (w0 col k-64), k>=67 -> 0. (3 K-steps, padded to 96.)
__global__ __launch_bounds__(256) void k_prep(
    const float* w0,const float* b0,const float* g0,const float* bt0,
    const float* w1,const float* b1,const float* g1,const float* bt1,
    const float* w2,const float* b2,const float* g2,const float* bt2,
    float* biasf,float* gf,float* btf,float* stats,
    u16* Wb0h, u16* Wb0l, u16* Wb1h, u16* Wb1l, u16* Wb2h, u16* Wb2l)
{
  int tid=threadIdx.x;
  for (int i=tid;i<768;i+=256) stats[i]=0.f;
  // W0 B-fragments (64 out cols -> tn 0..3, 3 k-steps)
  for (int i=tid;i<6144;i+=256){
    int e=i&7, lane=(i>>3)&63, idx=i>>9;        // idx = tn*3 + k0
    int tn=idx/3, k0=idx%3;
    int col = tn*16 + (lane&15);
    int k   = k0*32 + ((lane>>4)&3)*8 + e;      // 0..95
    float v = 0.f;
    if (k < 64)            v = w0[col*67 + 3 + k];
    else if (k < 67)       v = w0[col*67 + (k-64)];
    u16 hib = f2bf(v);
    Wb0h[i] = hib;
    Wb0l[i] = f2bf(v - bf2f(hib));
  }
  // W1 B-fragments (64 cols -> tn 0..3)
  for (int i=tid;i<4096;i+=256){
    int e=i&7, lane=(i>>3)&63, k0=(i>>9)&1, tn=i>>10;
    int col = tn*16 + (lane&15);
    int k   = k0*32 + ((lane>>4)&3)*8 + e;
    float v = w1[col*64 + k];
    u16 hib = f2bf(v);
    Wb1h[i] = hib;
    Wb1l[i] = f2bf(v - bf2f(hib));
  }
  // W2 B-fragments (128 cols -> tn 0..7)
  for (int i=tid;i<8192;i+=256){
    int e=i&7, lane=(i>>3)&63, k0=(i>>9)&1, tn=i>>10;
    int col = tn*16 + (lane&15);
    int k   = k0*32 + ((lane>>4)&3)*8 + e;
    float v = w2[col*64 + k];
    u16 hib = f2bf(v);
    Wb2h[i] = hib;
    Wb2l[i] = f2bf(v - bf2f(hib));
  }
  if (tid<64){
    biasf[0*128+tid]=b0[tid]; gf[0*128+tid]=g0[tid]; btf[0*128+tid]=bt0[tid];
    biasf[1*128+tid]=b1[tid]; gf[1*128+tid]=g1[tid]; btf[1*128+tid]=bt1[tid];
  }
  if (tid<128){
    biasf[2*128+tid]=b2[tid]; gf[2*128+tid]=g2[tid]; btf[2*128+tid]=bt2[tid];
  }
}

// ------------------------------------------------------- feature transpose
__global__ __launch_bounds__(256) void k_tr(const float* __restrict__ feats, u16* __restrict__ featT)
{
  __shared__ float t[64][65];
  int bb=blockIdx.y, n0=blockIdx.x*64, tid=threadIdx.x;
  int a=tid&63, q=tid>>6;
  const float* fp = feats + (size_t)bb*CIN_*N_;
  #pragma unroll
  for (int s=0;s<16;s++){ int c=q*16+s; t[c][a]=fp[(size_t)c*N_ + n0 + a]; }
  __syncthreads();
  u16* op = featT + (size_t)bb*N_*CIN_;
  #pragma unroll
  for (int s=0;s<16;s++){ int n=q*16+s; op[(size_t)(n0+n)*CIN_ + a] = f2bf(t[a][n]); }
}

// ---------------------------------------------------------------- FPS (R1 measured-best, frozen)
__global__ __launch_bounds__(512) void k_fps(const float* __restrict__ xyz,
                                             float* __restrict__ nxyz, float* __restrict__ out0)
{
#pragma clang fp contract(off)
  __shared__ float sx[N_], sy[N_], sz[N_];
  __shared__ int sidx[M_];
  __shared__ u64 skey[2][8];
  int b=blockIdx.x, tid=threadIdx.x;
  const float* xp = xyz + (size_t)b*N_*3;
  for (int i=tid;i<N_;i+=512){ sx[i]=xp[i*3]; sy[i]=xp[i*3+1]; sz[i]=xp[i*3+2]; }
  __syncthreads();
  v2f px[8],py[8],pz[8],md[8];
  int base = tid*16;
  #pragma unroll
  for (int p=0;p<8;p++){
    px[p]=*(const v2f*)&sx[base+2*p];
    py[p]=*(const v2f*)&sy[base+2*p];
    pz[p]=*(const v2f*)&sz[base+2*p];
    v2f m0; m0[0]=BIGF; m0[1]=BIGF; md[p]=m0;
  }
  u32 invb = 0xFFFFFFFFu - (u32)base;
  int far=0;
  int lane=tid&63, wv=tid>>6;
  for (int step=0; step<M_; step++){
    if (tid==0) sidx[step]=far;          // PRE-update emission
    float cxs=sx[far], cys=sy[far], czs=sz[far];
    v2f cx; cx[0]=cxs; cx[1]=cxs;
    v2f cy; cy[0]=cys; cy[1]=cys;
    v2f cz; cz[0]=czs; cz[1]=czs;
    u64 kb=0;
    #pragma unroll
    for (int p=0;p<8;p++){
      v2f dx=px[p]-cx, dy=py[p]-cy, dz=pz[p]-cz;
      v2f d=(dx*dx+dy*dy)+dz*dz;         // contract off: same assoc as ((xx+yy)+zz)
      v2f m=__builtin_elementwise_min(md[p],d);
      md[p]=m;
      u64 k0=((u64)__float_as_uint(m[0])<<32)|(u64)(invb-(u32)(2*p));
      u64 k1=((u64)__float_as_uint(m[1])<<32)|(u64)(invb-(u32)(2*p+1));
      u64 kp=(k1>k0)?k1:k0;              // equal dist -> k0 (lower idx) wins: larger ~idx
      kb=(kp>kb)?kp:kb;
    }
    kb = wave_max_key(kb);
    int par = step & 1;
    if (lane==63) skey[par][wv]=kb;
    __syncthreads();                     // single barrier per step
    u64 a0=skey[par][0],a1=skey[par][1],a2=skey[par][2],a3=skey[par][3];
    u64 a4=skey[par][4],a5=skey[par][5],a6=skey[par][6],a7=skey[par][7];
    a0=(a1>a0)?a1:a0; a2=(a3>a2)?a3:a2; a4=(a5>a4)?a5:a4; a6=(a7>a6)?a7:a6;
    a0=(a2>a0)?a2:a0; a4=(a6>a4)?a6:a4;
    a0=(a4>a0)?a4:a0;
    far = (int)(0xFFFFFFFFu - (u32)(a0 & 0xFFFFFFFFull));
  }
  for (int i=tid;i<M_;i+=512){
    int id = sidx[i];
    float x=sx[id], y=sy[id], z=sz[id];
    size_t o=(size_t)(b*M_+i)*3;
    nxyz[o]=x; nxyz[o+1]=y; nxyz[o+2]=z;
    out0[o]=x; out0[o+1]=y; out0[o+2]=z;
  }
}

// ---------------------------------------------------------------- ball query
#define BQCAP 512
__global__ __launch_bounds__(512) void k_bq(const float* __restrict__ xyz, const float* __restrict__ nxyz,
                                            int* __restrict__ knn)
{
  __shared__ float4 sP[N_];
  __shared__ float candd[8][BQCAP];
  __shared__ u16  candi[8][BQCAP];
  int tid=threadIdx.x;
  int cid0 = blockIdx.x*8;
  int b = cid0 >> 11;
  const float* xp = xyz + (size_t)b*N_*3;
  for (int i=tid;i<N_;i+=512){
    float x=xp[i*3], y=xp[i*3+1], z=xp[i*3+2];
    float x2 = __fmul_rn(x,x);
    x2 = __fadd_rn(x2, __fmul_rn(y,y));
    x2 = __fadd_rn(x2, __fmul_rn(z,z));
    sP[i]=make_float4(x,y,z,x2);
  }
  __syncthreads();
  int w=tid>>6, lane=tid&63;
  int cid = cid0 + w;
  float cx=nxyz[(size_t)cid*3], cy=nxyz[(size_t)cid*3+1], cz=nxyz[(size_t)cid*3+2];
  float c2 = __fmul_rn(cx,cx);
  c2 = __fadd_rn(c2, __fmul_rn(cy,cy));
  c2 = __fadd_rn(c2, __fmul_rn(cz,cz));
  int cnt=0;
  for (int i0=0;i0<N_;i0+=64){
    int i=i0+lane;
    float4 p=sP[i];
    float dot = __fmul_rn(cx,p.x);
    dot = __fadd_rn(dot, __fmul_rn(cy,p.y));
    dot = __fadd_rn(dot, __fmul_rn(cz,p.z));
    float d2 = __fsub_rn(__fadd_rn(c2,p.w), __fmul_rn(2.0f,dot));
    float d = sqrtf(fmaxf(d2,0.f));
    bool in = (d <= 0.4f);
    u64 msk = __ballot(in);
    int pos = cnt + __popcll(msk & ((1ull<<lane)-1ull));
    if (in && pos<BQCAP){ candd[w][pos]=d; candi[w][pos]=(u16)i; }
    cnt += __popcll(msk);
  }
  int R = cnt<BQCAP ? cnt : BQCAP;
  int* kout = knn + (size_t)cid*NS_;
  if (R >= NS_){
    for (int s=0;s<NS_;s++){
      u64 kb = ~0ull;                    // min identity
      for (int j=lane;j<R;j+=64){
        float v=candd[w][j];
        u64 k = ((u64)__float_as_uint(v)<<32) | (u64)(u32)j;
        kb = (k<kb)?k:kb;
      }
      u64 inv = wave_max_key(~kb);       // min via complemented max
      if (lane==63){
        u64 kw = ~inv;
        int bpp = (int)(u32)(kw & 0xFFFFFFFFull);
        kout[s]=candi[w][bpp];
        candd[w][bpp]=3e38f;             // same-wave DS in-order: visible next pass
      }
    }
  } else {
    if (lane<R) kout[lane]=candi[w][lane];
    int need = NS_-R, slot = R;
    for (int i0=0; i0<N_ && need>0; i0+=64){
      int i=i0+lane;
      float4 p=sP[i];
      float dot = __fmul_rn(cx,p.x);
      dot = __fadd_rn(dot, __fmul_rn(cy,p.y));
      dot = __fadd_rn(dot, __fmul_rn(cz,p.z));
      float d2 = __fsub_rn(__fadd_rn(c2,p.w), __fmul_rn(2.0f,dot));
      float d = sqrtf(fmaxf(d2,0.f));
      bool in = (d <= 0.4f);
      u64 mm = __ballot(!in);
      while (mm && need>0){
        int bpos = __ffsll((long long)mm)-1;
        if (lane==0) kout[slot] = i0+bpos;
        slot++; need--;
        mm &= mm-1;
      }
    }
  }
}

// ---------------------------------------------------------------- layer 0: MFMA (gather+concat fused)
// mm1/mm2a template. 8192 blocks x 64 rows, 4 waves. Staged layout per row (256B stride,
// swizzled ^((row&7)<<4)): cols 0..63 = gathered feat (bf16 copy), 64..66 = xyz_norm
// (f2bf(x-c)), 67..95 = zeros; 3 K-steps of 32. Weight frags Wb0h/Wb0l match this order.
__global__ __launch_bounds__(256) void k_mm0(const float* __restrict__ xyz, const u16* __restrict__ featT,
                                             const int* __restrict__ knn, const float* __restrict__ nxyz,
                                             const u16* __restrict__ Wb0h, const u16* __restrict__ Wb0l,
                                             const float* __restrict__ bias0, u16* __restrict__ Y0)
{
  __shared__ u16 Xs[64*128];     // 16KB, row stride 256B, swizzled
  __shared__ u16 WH[12*64*8];    // 12KB [tn*3+k0][lane][e]
  __shared__ u16 WL[12*64*8];    // 12KB
  int tid=threadIdx.x;
  {
    const uint4* s4=(const uint4*)Wb0h; uint4* d4=(uint4*)WH;
    const uint4* s5=(const uint4*)Wb0l; uint4* d5=(uint4*)WL;
    for (int i=tid;i<768;i+=256){ d4[i]=s4[i]; d5[i]=s5[i]; }
  }
  size_t base=(size_t)blockIdx.x*64;
  {
    int rl=tid>>2, t=tid&3;                 // 4 threads per row
    int row=(int)base+rl;
    int bm = row>>5, b = row>>16;
    int n  = knn[row];
    const uint4* fp = (const uint4*)(featT + ((size_t)b*N_ + n)*CIN_);
    char* xr = (char*)Xs + rl*256;
    u32 swz = (u32)((rl&7)<<4);
    // feat bytes t*32 .. t*32+31 (two 16B granules)
    uint4 v0=fp[t*2], v1=fp[t*2+1];
    *(uint4*)(xr + ((t*32)    ^ swz)) = v0;
    *(uint4*)(xr + ((t*32+16) ^ swz)) = v1;
    // pad granule at byte 128+t*16: t==0 carries xyz_norm, rest zero
    uint4 pz = make_uint4(0u,0u,0u,0u);
    if (t==0){
      const float* cp = nxyz + (size_t)bm*3;
      const float* xp = xyz + ((size_t)b*N_ + n)*3;
      u32 w01 = (u32)f2bf(xp[0]-cp[0]) | ((u32)f2bf(xp[1]-cp[1])<<16);
      u32 w2  = (u32)f2bf(xp[2]-cp[2]);
      pz.x = w01; pz.y = w2;
    }
    *(uint4*)(xr + ((128+t*16) ^ swz)) = pz;
  }
  __syncthreads();
  int w=tid>>6, lane=tid&63;
  f32x4 acc[4];
  #pragma unroll
  for (int tn=0;tn<4;tn++){ acc[tn][0]=0.f; acc[tn][1]=0.f; acc[tn][2]=0.f; acc[tn][3]=0.f; }
  int arow = w*16 + (lane&15);
  u32 aswz = (u32)((arow&7)<<4);
  #pragma unroll
  for (int k0=0;k0<3;k0++){
    int aoff = arow*256 + (int)(((u32)((k0*32 + ((lane>>4)&3)*8)*2)) ^ aswz);
    bf16x8 a = *(const bf16x8*)((const char*)Xs + aoff);
    #pragma unroll
    for (int tn=0;tn<4;tn++){
      bf16x8 bl = *(const bf16x8*)&WL[((tn*3+k0)*64+lane)*8];
      bf16x8 bh = *(const bf16x8*)&WH[((tn*3+k0)*64+lane)*8];
      acc[tn] = __builtin_amdgcn_mfma_f32_16x16x32_bf16(a, bl, acc[tn], 0,0,0);
      acc[tn] = __builtin_amdgcn_mfma_f32_16x16x32_bf16(a, bh, acc[tn], 0,0,0);
    }
  }
  #pragma unroll
  for (int tn=0;tn<4;tn++){
    int col = tn*16 + (lane&15);
    float bb = bias0[col];
    #pragma unroll
    for (int j=0;j<4;j++){
      int row = w*16 + (lane>>4)*4 + j;
      Y0[(base+row)*64 + col] = f2bf(acc[tn][j] + bb);
    }
  }
}

// ---------------------------------------------------------------- channel stats (sum, sumsq)
template<int C>
__global__ __launch_bounds__(256) void k_stats(const u16* __restrict__ Y, float* __restrict__ statsOut)
{
  __shared__ float sred[4][128];
  int tid=threadIdx.x;
  int c0=(tid&7)*8;          // 8 channels per thread
  int rg=tid>>3;             // 32 row-groups per block
  float s[8], ss[8];
  #pragma unroll
  for (int k=0;k<8;k++){ s[k]=0.f; ss[k]=0.f; }
  for (size_t r=(size_t)blockIdx.x*32+rg; r<ROWS_; r+=(size_t)gridDim.x*32){
    uint4 v=*(const uint4*)&Y[r*64+c0];
    u32 a[4]={v.x,v.y,v.z,v.w};
    #pragma unroll
    for (int q=0;q<4;q++){
      float lo=bf2f((u16)(a[q]&0xFFFFu));
      float hi=bf2f((u16)(a[q]>>16));
      s[q*2]+=lo;   ss[q*2]+=lo*lo;
      s[q*2+1]+=hi; ss[q*2+1]+=hi*hi;
    }
  }
  #pragma unroll
  for (int off=32; off>=8; off>>=1){
    #pragma unroll
    for (int k=0;k<8;k++){
      s[k]+=__shfl_down(s[k],off);
      ss[k]+=__shfl_down(ss[k],off);
    }
  }
  int lane=tid&63, wv=tid>>6;
  if (lane<8){
    #pragma unroll
    for (int k=0;k<8;k++){
      int ch=lane*8+k;
      sred[wv][ch]=s[k];
      sred[wv][64+ch]=ss[k];
    }
  }
  __syncthreads();
  if (tid<128){
    float a=sred[0][tid]+sred[1][tid]+sred[2][tid]+sred[3][tid];
    int ch=tid&63, which=tid>>6;
    atomicAdd(&statsOut[ch*2+which], a);
  }
}

// ---------------------------------------------------------------- layer 1: MFMA (proven R5)
__global__ __launch_bounds__(256) void k_mm1(u16* __restrict__ Y,
                                             const u16* __restrict__ Wb1h, const u16* __restrict__ Wb1l,
                                             const float* __restrict__ bias1, const float* __restrict__ gf0,
                                             const float* __restrict__ btf0, const float* __restrict__ stats0)
{
  __shared__ u16 Xs[64*64];      // 8KB, swizzled
  __shared__ u16 WH[8*64*8];     // 8KB  [tn*2+k0][lane][e]
  __shared__ u16 WL[8*64*8];     // 8KB
  __shared__ float sc[64], sh[64];
  int tid=threadIdx.x;
  if (tid<64){
    float mu = stats0[tid*2]*INV_ROWS;
    float var= stats0[tid*2+1]*INV_ROWS - mu*mu;
    float rs = 1.0f/sqrtf(var+EPSF);
    float s  = rs*gf0[tid];
    sc[tid]=s; sh[tid]=btf0[tid]-mu*s;
  }
  {
    const uint4* sh4=(const uint4*)Wb1h; uint4* dh4=(uint4*)WH;
    const uint4* sl4=(const uint4*)Wb1l; uint4* dl4=(uint4*)WL;
    dh4[tid]=sh4[tid]; dh4[tid+256]=sh4[tid+256];
    dl4[tid]=sl4[tid]; dl4[tid+256]=sl4[tid+256];
  }
  __syncthreads();
  size_t base=(size_t)blockIdx.x*64;
  for (int i=tid;i<512;i+=256){
    int rl=i>>3, c0=(i&7)*8;
    uint4 v=*(const uint4*)(Y + (base+rl)*64 + c0);
    u32 arr[4]={v.x,v.y,v.z,v.w};
    u32 pk[4];
    #pragma unroll
    for (int q=0;q<4;q++){
      int cc=c0+q*2;
      float lo=bf2f((u16)(arr[q]&0xFFFFu));
      float hi=bf2f((u16)(arr[q]>>16));
      lo=fmaxf(0.f, lo*sc[cc]+sh[cc]);
      hi=fmaxf(0.f, hi*sc[cc+1]+sh[cc+1]);
      pk[q] = (u32)f2bf(lo) | ((u32)f2bf(hi)<<16);
    }
    uint4 o4; o4.x=pk[0]; o4.y=pk[1]; o4.z=pk[2]; o4.w=pk[3];
    int byteoff = rl*128 + ((c0*2) ^ ((rl&7)<<4));
    *(uint4*)((char*)Xs + byteoff) = o4;
  }
  __syncthreads();
  int w=tid>>6, lane=tid&63;
  f32x4 acc[4];
  #pragma unroll
  for (int tn=0;tn<4;tn++){ acc[tn][0]=0.f; acc[tn][1]=0.f; acc[tn][2]=0.f; acc[tn][3]=0.f; }
  int arow = w*16 + (lane&15);
  #pragma unroll
  for (int k0=0;k0<2;k0++){
    int aoff = arow*128 + ((k0*64 + (lane>>4)*16) ^ ((arow&7)<<4));
    bf16x8 a = *(const bf16x8*)((const char*)Xs + aoff);
    #pragma unroll
    for (int tn=0;tn<4;tn++){
      bf16x8 bl = *(const bf16x8*)&WL[((tn*2+k0)*64+lane)*8];
      bf16x8 bh = *(const bf16x8*)&WH[((tn*2+k0)*64+lane)*8];
      acc[tn] = __builtin_amdgcn_mfma_f32_16x16x32_bf16(a, bl, acc[tn], 0,0,0);
      acc[tn] = __builtin_amdgcn_mfma_f32_16x16x32_bf16(a, bh, acc[tn], 0,0,0);
    }
  }
  #pragma unroll
  for (int tn=0;tn<4;tn++){
    int col = tn*16 + (lane&15);
    float bb = bias1[col];
    #pragma unroll
    for (int j=0;j<4;j++){
      int row = w*16 + (lane>>4)*4 + j;
      Y[(base+row)*64 + col] = f2bf(acc[tn][j] + bb);
    }
  }
}

// ---------------------------------------------------------------- layer 2: MFMA + stats + RAW maxpool (proven R6)
__global__ __launch_bounds__(256) void k_mm2a(const u16* __restrict__ Y1,
                                              const u16* __restrict__ Wb2h, const u16* __restrict__ Wb2l,
                                              const float* __restrict__ bias2, const float* __restrict__ gf1,
                                              const float* __restrict__ btf1, const float* __restrict__ stats1,
                                              float* __restrict__ stats2, float* __restrict__ out1)
{
  __shared__ u16 Xs[64*64];       // 8KB swizzled bf16 (row stride 128B)
  __shared__ u16 WH[8192];        // 16KB [tn*2+k0][lane][e], tn 0..7
  __shared__ u16 WL[8192];        // 16KB
  __shared__ float Ys[64*128];    // 32KB raw y, swizzled (row stride 512B)
  __shared__ float sc[64], sh[64];
  __shared__ float sred[512];
  int tid=threadIdx.x;
  if (tid<64){
    float mu = stats1[tid*2]*INV_ROWS;
    float var= stats1[tid*2+1]*INV_ROWS - mu*mu;
    float rs = 1.0f/sqrtf(var+EPSF);
    float s  = rs*gf1[tid];
    sc[tid]=s; sh[tid]=btf1[tid]-mu*s;
  }
  {
    const uint4* s4=(const uint4*)Wb2h; uint4* d4=(uint4*)WH;
    const uint4* s5=(const uint4*)Wb2l; uint4* d5=(uint4*)WL;
    for (int i=tid;i<1024;i+=256){ d4[i]=s4[i]; d5[i]=s5[i]; }
  }
  int w=tid>>6, lane=tid&63;
  int pg=tid>>7, po=tid&127;      // pool assignment: group (0,1), channel
  float accSum=0.f, accSq=0.f;    // per-thread channel stats across tiles
  __syncthreads();
  for (int tile=blockIdx.x; tile<8192; tile+=gridDim.x){
    size_t base=(size_t)tile*64;
    for (int i=tid;i<512;i+=256){
      int rl=i>>3, c0=(i&7)*8;
      uint4 v=*(const uint4*)(Y1 + (base+rl)*64 + c0);
      u32 arr[4]={v.x,v.y,v.z,v.w};
      u32 pk[4];
      #pragma unroll
      for (int q=0;q<4;q++){
        int cc=c0+q*2;
        float lo=bf2f((u16)(arr[q]&0xFFFFu));
        float hi=bf2f((u16)(arr[q]>>16));
        lo=fmaxf(0.f, lo*sc[cc]+sh[cc]);
        hi=fmaxf(0.f, hi*sc[cc+1]+sh[cc+1]);
        pk[q] = (u32)f2bf(lo) | ((u32)f2bf(hi)<<16);
      }
      uint4 o4; o4.x=pk[0]; o4.y=pk[1]; o4.z=pk[2]; o4.w=pk[3];
      int byteoff = rl*128 + ((c0*2) ^ ((rl&7)<<4));
      *(uint4*)((char*)Xs + byteoff) = o4;
    }
    __syncthreads();
    f32x4 acc[8];
    #pragma unroll
    for (int tn=0;tn<8;tn++){ acc[tn][0]=0.f; acc[tn][1]=0.f; acc[tn][2]=0.f; acc[tn][3]=0.f; }
    int arow = w*16 + (lane&15);
    #pragma unroll
    for (int k0=0;k0<2;k0++){
      int aoff = arow*128 + ((k0*64 + (lane>>4)*16) ^ ((arow&7)<<4));
      bf16x8 a = *(const bf16x8*)((const char*)Xs + aoff);
      #pragma unroll
      for (int tn=0;tn<8;tn++){
        bf16x8 bl = *(const bf16x8*)&WL[((tn*2+k0)*64+lane)*8];
        bf16x8 bh = *(const bf16x8*)&WH[((tn*2+k0)*64+lane)*8];
        acc[tn] = __builtin_amdgcn_mfma_f32_16x16x32_bf16(a, bl, acc[tn], 0,0,0);
        acc[tn] = __builtin_amdgcn_mfma_f32_16x16x32_bf16(a, bh, acc[tn], 0,0,0);
      }
    }
    #pragma unroll
    for (int tn=0;tn<8;tn++){
      int col = tn*16 + (lane&15);
      float bb = bias2[col];
      #pragma unroll
      for (int j=0;j<4;j++){
        int row = w*16 + (lane>>4)*4 + j;
        int byteoff = row*512 + ((col*4) ^ ((row&7)<<4));
        *(float*)((char*)Ys + byteoff) = acc[tn][j] + bb;
      }
    }
    __syncthreads();
    {
      float mx=-3e38f;
      #pragma unroll 4
      for (int k=0;k<32;k++){
        int row = pg*32 + k;
        int byteoff = row*512 + ((po*4) ^ ((row&7)<<4));
        float y = *(const float*)((const char*)Ys + byteoff);
        accSum += y; accSq += y*y;
        mx = fmaxf(mx, y);
      }
      int bm = tile*2 + pg; int bi = bm>>11, m = bm&2047;
      out1[((size_t)bi*128+po)*M_ + m] = mx;
    }
    __syncthreads();   // protect Xs/Ys for next tile
  }
  sred[tid]      = accSum;
  sred[256+tid]  = accSq;
  __syncthreads();
  if (tid<128){
    float s = sred[tid] + sred[tid+128];
    float q = sred[256+tid] + sred[256+tid+128];
    atomicAdd(&stats2[tid*2],   s);
    atomicAdd(&stats2[tid*2+1], q);
  }
}

// ---------------------------------------------------------------- final pool: in-place BN2+ReLU on raw maxes
__global__ __launch_bounds__(256) void k_pool(float* __restrict__ out1, const float* __restrict__ stats2,
                                              const float* __restrict__ gf2, const float* __restrict__ btf2)
{
  int idx = blockIdx.x*256 + threadIdx.x;     // 8*128*2048 = 2097152 elements
  int o = (idx >> 11) & 127;
  float mu = stats2[o*2]*INV_ROWS;
  float var= stats2[o*2+1]*INV_ROWS - mu*mu;
  float rs = 1.0f/sqrtf(var+EPSF);
  float s  = rs*gf2[o];
  float sh = btf2[o]-mu*s;
  out1[idx] = fmaxf(0.f, out1[idx]*s + sh);
}

// ---------------------------------------------------------------- launch
extern "C" void kernel_launch(void* const* d_in, const int* in_sizes, int n_in,
                              void* d_out, int out_size, void* d_ws, size_t ws_size,
                              hipStream_t stream)
{
  (void)in_sizes; (void)n_in; (void)out_size; (void)ws_size;
  const float* xyz =(const float*)d_in[0];
  const float* feat=(const float*)d_in[1];
  const float* w0=(const float*)d_in[2],  *b0=(const float*)d_in[3],  *g0=(const float*)d_in[4],  *bt0=(const float*)d_in[5];
  const float* w1=(const float*)d_in[6],  *b1=(const float*)d_in[7],  *g1=(const float*)d_in[8],  *bt1=(const float*)d_in[9];
  const float* w2=(const float*)d_in[10], *b2=(const float*)d_in[11], *g2=(const float*)d_in[12], *bt2=(const float*)d_in[13];
  float* out0=(float*)d_out;
  float* out1=out0 + (size_t)B_*M_*3;

  char* ws=(char*)d_ws;
  float* nxyz =(float*)(ws);              // 196608 B used
  u16*   Wb1h =(u16*)  (ws + 196608);     // 8192 B
  u16*   Wb1l =(u16*)  (ws + 204800);     // 8192 B
  u16*   Wb2h =(u16*)  (ws + 212992);     // 16384 B
  u16*   Wb2l =(u16*)  (ws + 229376);     // 16384 B (ends 245760 < 262144)
  int*   knn  =(int*)  (ws + 262144);     // 2097152
  u16*   Wb0h =(u16*)  (ws + 2359296);    // 12288 B (reuses dead Wt0 slot)
  u16*   Wb0l =(u16*)  (ws + 2376704);    // 12288 B (reuses dead Wt1 slot)
  float* biasf=(float*)(ws + 2425856);    // 1536
  float* gfp  =(float*)(ws + 2427392);    // 1536
  float* btfp =(float*)(ws + 2428928);    // 1536
  float* stats=(float*)(ws + 2430464);    // 3072
  u16*   featT=(u16*)  (ws + 2433536);    // 8388608
  u16*   Y0   =(u16*)  (ws + 10822144);   // 67108864  (total ~78 MB)

  k_prep<<<1,256,0,stream>>>(w0,b0,g0,bt0,w1,b1,g1,bt1,w2,b2,g2,bt2,biasf,gfp,btfp,stats,
                             Wb0h,Wb0l,Wb1h,Wb1l,Wb2h,Wb2l);
  k_tr<<<dim3(128,8),256,0,stream>>>(feat, featT);
  k_fps<<<B_,512,0,stream>>>(xyz, nxyz, out0);
  k_bq<<<2048,512,0,stream>>>(xyz, nxyz, knn);
  k_mm0<<<8192,256,0,stream>>>(xyz, featT, knn, nxyz, Wb0h, Wb0l, biasf+0, Y0);
  k_stats<64><<<128,256,0,stream>>>(Y0, stats+0);
  k_mm1<<<8192,256,0,stream>>>(Y0, Wb1h, Wb1l, biasf+128, gfp+0, btfp+0, stats+0);
  k_stats<64><<<128,256,0,stream>>>(Y0, stats+256);
  k_mm2a<<<512,256,0,stream>>>(Y0, Wb2h, Wb2l, biasf+256, gfp+128, btfp+128, stats+256, stats+512, out1);
  k_pool<<<8192,256,0,stream>>>(out1, stats+512, gfp+256, btfp+256);
}